// Round 4
// baseline (444.543 us; speedup 1.0000x reference)
//
#include <hip/hip_runtime.h>
#include <cstdint>
#include <cstddef>

#define NEG_SLOPE 0.2f

__device__ __forceinline__ float elu_f(float x) {
    return x > 0.f ? x : expm1f(x);
}

// ---------------------------------------------------------------------------
// Encoder: h0 = elu(elu(x @ W1 + b1) @ W2 + b2), x:[N,8] -> [N,64]
// ---------------------------------------------------------------------------
__global__ void encoder_kernel(const float* __restrict__ x,
                               const float* __restrict__ W1, const float* __restrict__ b1,
                               const float* __restrict__ W2, const float* __restrict__ b2,
                               float* __restrict__ h0, int n_nodes) {
    int i = blockIdx.x * blockDim.x + threadIdx.x;
    if (i >= n_nodes) return;
    const float4* xp = (const float4*)(x + (size_t)i * 8);
    float4 x0 = xp[0], x1 = xp[1];
    float xi[8] = {x0.x, x0.y, x0.z, x0.w, x1.x, x1.y, x1.z, x1.w};
    float h1[32];
#pragma unroll
    for (int j = 0; j < 32; ++j) {
        float a = b1[j];
#pragma unroll
        for (int k = 0; k < 8; ++k) a += xi[k] * W1[k * 32 + j];
        h1[j] = elu_f(a);
    }
    float* dst = h0 + (size_t)i * 64;
    for (int j = 0; j < 64; ++j) {
        float a = b2[j];
#pragma unroll
        for (int k = 0; k < 32; ++k) a += h1[k] * W2[k * 64 + j];
        dst[j] = elu_f(a);
    }
}

// ---------------------------------------------------------------------------
// CSR build (by destination), reused across all 3 GAT layers.
// ---------------------------------------------------------------------------
__global__ void zero_detect_kernel(const int* __restrict__ ei, int* __restrict__ cnt,
                                   int* __restrict__ flag, int n) {
    int i = blockIdx.x * blockDim.x + threadIdx.x;
    if (i < n) cnt[i] = 0;
    if (i == 0) {
        int acc = 0;
#pragma unroll
        for (int k = 0; k < 8; ++k) acc |= ei[2 * k + 1];
        flag[0] = (acc == 0) ? 1 : 0;  // high words all zero -> int64 layout
    }
}

__global__ void count_kernel(const int* __restrict__ ei, const int* __restrict__ flag,
                             int E, int Etot, int* __restrict__ cnt) {
    int e = blockIdx.x * blockDim.x + threadIdx.x;
    if (e >= Etot) return;
    int d;
    if (e < E) d = flag[0] ? ei[2 * (size_t)(E + e)] : ei[E + e];
    else       d = e - E;  // self loop
    atomicAdd(&cnt[d], 1);
}

#define SCAN_B 256
__global__ void scan1_kernel(const int* __restrict__ cnt, int* __restrict__ incl,
                             int* __restrict__ bsum, int n) {
    __shared__ int sd[SCAN_B];
    int t = threadIdx.x;
    int g = blockIdx.x * SCAN_B + t;
    int v = (g < n) ? cnt[g] : 0;
    sd[t] = v;
    __syncthreads();
    for (int off = 1; off < SCAN_B; off <<= 1) {
        int add = (t >= off) ? sd[t - off] : 0;
        __syncthreads();
        sd[t] += add;
        __syncthreads();
    }
    if (g < n) incl[g] = sd[t];
    if (t == SCAN_B - 1) bsum[blockIdx.x] = sd[SCAN_B - 1];
}

__global__ void scan2_kernel(const int* __restrict__ bsum, int* __restrict__ boff, int nb) {
    __shared__ int sd[256];
    int t = threadIdx.x;
    int v = (t < nb) ? bsum[t] : 0;
    sd[t] = v;
    __syncthreads();
    for (int off = 1; off < 256; off <<= 1) {
        int add = (t >= off) ? sd[t - off] : 0;
        __syncthreads();
        sd[t] += add;
        __syncthreads();
    }
    if (t < nb) boff[t] = sd[t] - v;  // exclusive block offset
}

__global__ void scan3_kernel(const int* __restrict__ incl, const int* __restrict__ boff,
                             const int* __restrict__ cnt, int* __restrict__ rowptr,
                             int* __restrict__ cursor, int n) {
    int i = blockIdx.x * SCAN_B + threadIdx.x;
    if (i >= n) return;
    int e = incl[i] + boff[blockIdx.x];
    rowptr[i + 1] = e;
    cursor[i] = e - cnt[i];
    if (i == 0) rowptr[0] = 0;
}

__global__ void fill_kernel(const int* __restrict__ ei, const int* __restrict__ flag,
                            int E, int Etot, int* __restrict__ cursor,
                            int* __restrict__ col) {
    int e = blockIdx.x * blockDim.x + threadIdx.x;
    if (e >= Etot) return;
    int s, d;
    if (e < E) {
        if (flag[0]) { s = ei[2 * (size_t)e]; d = ei[2 * (size_t)(E + e)]; }
        else         { s = ei[e];             d = ei[E + e]; }
    } else {
        s = d = e - E;
    }
    int pos = atomicAdd(&cursor[d], 1);
    col[pos] = s;
}

// ---------------------------------------------------------------------------
// Attention dots: asrc[n,h] = bin[n] . (W_h @ att_s_h), same for adst.
// Folded vectors vsd[k*8+j] (j<4: src head j, j>=4: dst head j-4) are
// recomputed per block in LDS (cheap, W is L2-hot). One wave = 8 nodes x 8
// outputs; block = 32 nodes.
// ---------------------------------------------------------------------------
__global__ __launch_bounds__(256) void gat_dots_kernel(
    const float* __restrict__ bin, const float* __restrict__ W,
    const float* __restrict__ att_s, const float* __restrict__ att_d,
    float* __restrict__ asrc, float* __restrict__ adst, int n_nodes) {
    __shared__ float vsd[512];  // [k][j] layout: k*8+j (bank-spread reads)
    const int t = threadIdx.x;
#pragma unroll
    for (int u = 0; u < 2; ++u) {
        const int e = t * 2 + u;
        const int k = e >> 3, j = e & 7, h = j & 3;
        const float* av = (j < 4) ? att_s : att_d;
        float s = 0.f;
#pragma unroll
        for (int cc = 0; cc < 64; ++cc) s += W[k * 256 + h * 64 + cc] * av[h * 64 + cc];
        vsd[k * 8 + j] = s;
    }
    __syncthreads();
    const int lane = t & 63, wv = t >> 6;
    const int n = blockIdx.x * 32 + wv * 8 + (lane >> 3);
    const int j = lane & 7, h = j & 3;
    if (n < n_nodes) {
        const float* br = bin + (size_t)n * 64;
        float a = 0.f;
#pragma unroll 8
        for (int k = 0; k < 64; ++k) a += br[k] * vsd[k * 8 + j];
        if (j < 4) asrc[n * 4 + h] = a;
        else       adst[n * 4 + h] = a;
    }
}

// ---------------------------------------------------------------------------
// GAT aggregation v3: gathers RAW bin[src] (256B/edge, not projected 1KB).
// One wave per dst node (lane = channel k). Chunk of 64 edges: lane j
// prefetches col + per-head exp weights + den; serial 4-unrolled loop
// broadcasts (readlane) and gathers one dword per edge per lane.
// Writes per-head normalized sums g[n, h*64+k] (to be projected by post).
// ---------------------------------------------------------------------------
__global__ __launch_bounds__(256) void gat_agg_kernel(
    const float* __restrict__ bin, const float* __restrict__ asrc,
    const float* __restrict__ adst, const int* __restrict__ rowptr,
    const int* __restrict__ col, float* __restrict__ g, int n_nodes) {
    const int wid = threadIdx.x >> 6;
    const int lane = threadIdx.x & 63;
    const int n = blockIdx.x * 4 + wid;
    if (n >= n_nodes) return;
    const float4 ad4 = *(const float4*)(adst + (size_t)n * 4);
    const int start = rowptr[n], end = rowptr[n + 1];

    float acc0 = 0.f, acc1 = 0.f, acc2 = 0.f, acc3 = 0.f;
    float4 den4 = make_float4(0.f, 0.f, 0.f, 0.f);
    for (int base = start; base < end; base += 64) {
        const int cnt = min(64, end - base);
        int c = 0;
        float4 w4 = make_float4(0.f, 0.f, 0.f, 0.f);
        if (base + lane < end) {
            c = col[base + lane];
            const float4 av = *(const float4*)(asrc + (size_t)c * 4);
            float l0 = av.x + ad4.x; l0 = l0 > 0.f ? l0 : NEG_SLOPE * l0;
            float l1 = av.y + ad4.y; l1 = l1 > 0.f ? l1 : NEG_SLOPE * l1;
            float l2 = av.z + ad4.z; l2 = l2 > 0.f ? l2 : NEG_SLOPE * l2;
            float l3 = av.w + ad4.w; l3 = l3 > 0.f ? l3 : NEG_SLOPE * l3;
            w4.x = __expf(fminf(l0, 60.f));
            w4.y = __expf(fminf(l1, 60.f));
            w4.z = __expf(fminf(l2, 60.f));
            w4.w = __expf(fminf(l3, 60.f));
            den4.x += w4.x; den4.y += w4.y; den4.z += w4.z; den4.w += w4.w;
        }
        int j = 0;
        for (; j + 4 <= cnt; j += 4) {
            const int s0 = __shfl(c, j), s1 = __shfl(c, j + 1);
            const int s2 = __shfl(c, j + 2), s3 = __shfl(c, j + 3);
            const float h0 = bin[(size_t)s0 * 64 + lane];
            const float h1 = bin[(size_t)s1 * 64 + lane];
            const float h2 = bin[(size_t)s2 * 64 + lane];
            const float h3 = bin[(size_t)s3 * 64 + lane];
            acc0 += __shfl(w4.x, j) * h0 + __shfl(w4.x, j + 1) * h1
                  + __shfl(w4.x, j + 2) * h2 + __shfl(w4.x, j + 3) * h3;
            acc1 += __shfl(w4.y, j) * h0 + __shfl(w4.y, j + 1) * h1
                  + __shfl(w4.y, j + 2) * h2 + __shfl(w4.y, j + 3) * h3;
            acc2 += __shfl(w4.z, j) * h0 + __shfl(w4.z, j + 1) * h1
                  + __shfl(w4.z, j + 2) * h2 + __shfl(w4.z, j + 3) * h3;
            acc3 += __shfl(w4.w, j) * h0 + __shfl(w4.w, j + 1) * h1
                  + __shfl(w4.w, j + 2) * h2 + __shfl(w4.w, j + 3) * h3;
        }
        for (; j < cnt; ++j) {
            const int s = __shfl(c, j);
            const float hv = bin[(size_t)s * 64 + lane];
            acc0 += __shfl(w4.x, j) * hv;
            acc1 += __shfl(w4.y, j) * hv;
            acc2 += __shfl(w4.z, j) * hv;
            acc3 += __shfl(w4.w, j) * hv;
        }
    }
#pragma unroll
    for (int off = 1; off < 64; off <<= 1) {
        den4.x += __shfl_xor(den4.x, off);
        den4.y += __shfl_xor(den4.y, off);
        den4.z += __shfl_xor(den4.z, off);
        den4.w += __shfl_xor(den4.w, off);
    }
    float* gr = g + (size_t)n * 256 + lane;
    gr[0]   = acc0 / (den4.x + 1e-16f);
    gr[64]  = acc1 / (den4.y + 1e-16f);
    gr[128] = acc2 / (den4.z + 1e-16f);
    gr[192] = acc3 / (den4.w + 1e-16f);
}

// ---------------------------------------------------------------------------
// GAT post-projection: out[n,c] = 0.25 * sum_{h,k} g[n,h*64+k] * W[k,h*64+c]
//                               + bias[c] + bin[n,c]  (residual)
// LDS GEMM: block = 64 nodes x 64 cols, K=256 in 2 slabs of 128.
// gS [64 nodes][stride 260] (pad breaks bank collisions), Wp slab 128x64.
// Micro-tile 2 nodes x 8 cols per thread (256 threads).
// ---------------------------------------------------------------------------
#define PSR 260
__global__ __launch_bounds__(256) void gat_post_kernel(
    const float* __restrict__ g, const float* __restrict__ W,
    const float* __restrict__ bias, const float* __restrict__ xin,
    float* __restrict__ out, int n_nodes) {
    __shared__ float gS[64 * PSR];   // 66,560 B
    __shared__ float Wp[128 * 64];   // 32,768 B
    const int t = threadIdx.x;
    const int n0 = blockIdx.x * 64;

    // stage gS: wave per node per pass, coalesced 1KB reads
    {
        const int c4 = t & 63;
        const int nw = t >> 6;
        for (int p = 0; p < 16; ++p) {
            const int nl = p * 4 + nw;
            const int n = n0 + nl;
            float4 v = make_float4(0.f, 0.f, 0.f, 0.f);
            if (n < n_nodes) v = *(const float4*)(g + (size_t)n * 256 + c4 * 4);
            *(float4*)(gS + nl * PSR + c4 * 4) = v;
        }
    }

    const int cg = t & 7;    // 8 col groups x 8 cols
    const int ng = t >> 3;   // 32 node groups x 2 nodes
    float acc[2][8];
#pragma unroll
    for (int i = 0; i < 2; ++i)
#pragma unroll
        for (int q = 0; q < 8; ++q) acc[i][q] = 0.f;

    for (int slab = 0; slab < 2; ++slab) {
        __syncthreads();
        // stage Wp[kl][c] = W[k, h*64+c] for kap = slab*128 + kl
#pragma unroll
        for (int j = 0; j < 8; ++j) {
            const int f4 = j * 256 + t;           // float4 index, 0..2047
            const int kl = f4 >> 4;               // 0..127
            const int kap = slab * 128 + kl;
            const int h = kap >> 6, kk = kap & 63;
            const int c = (f4 & 15) * 4;
            *(float4*)(Wp + kl * 64 + c) = *(const float4*)(W + kk * 256 + h * 64 + c);
        }
        __syncthreads();
#pragma unroll 4
        for (int kl = 0; kl < 128; ++kl) {
            const int kap = slab * 128 + kl;
            const float a0 = gS[(ng * 2 + 0) * PSR + kap];
            const float a1 = gS[(ng * 2 + 1) * PSR + kap];
            const float4 b0 = *(const float4*)(Wp + kl * 64 + cg * 8);
            const float4 b1 = *(const float4*)(Wp + kl * 64 + cg * 8 + 4);
            acc[0][0] += a0 * b0.x; acc[0][1] += a0 * b0.y;
            acc[0][2] += a0 * b0.z; acc[0][3] += a0 * b0.w;
            acc[0][4] += a0 * b1.x; acc[0][5] += a0 * b1.y;
            acc[0][6] += a0 * b1.z; acc[0][7] += a0 * b1.w;
            acc[1][0] += a1 * b0.x; acc[1][1] += a1 * b0.y;
            acc[1][2] += a1 * b0.z; acc[1][3] += a1 * b0.w;
            acc[1][4] += a1 * b1.x; acc[1][5] += a1 * b1.y;
            acc[1][6] += a1 * b1.z; acc[1][7] += a1 * b1.w;
        }
    }

    const int c0 = cg * 8;
    const float4 bb0 = *(const float4*)(bias + c0);
    const float4 bb1 = *(const float4*)(bias + c0 + 4);
#pragma unroll
    for (int i = 0; i < 2; ++i) {
        const int n = n0 + ng * 2 + i;
        if (n >= n_nodes) continue;
        const float4 x0 = *(const float4*)(xin + (size_t)n * 64 + c0);
        const float4 x1 = *(const float4*)(xin + (size_t)n * 64 + c0 + 4);
        float4 o0, o1;
        o0.x = 0.25f * acc[i][0] + bb0.x + x0.x;
        o0.y = 0.25f * acc[i][1] + bb0.y + x0.y;
        o0.z = 0.25f * acc[i][2] + bb0.z + x0.z;
        o0.w = 0.25f * acc[i][3] + bb0.w + x0.w;
        o1.x = 0.25f * acc[i][4] + bb1.x + x1.x;
        o1.y = 0.25f * acc[i][5] + bb1.y + x1.y;
        o1.z = 0.25f * acc[i][6] + bb1.z + x1.z;
        o1.w = 0.25f * acc[i][7] + bb1.w + x1.w;
        *(float4*)(out + (size_t)n * 64 + c0) = o0;
        *(float4*)(out + (size_t)n * 64 + c0 + 4) = o1;
    }
}

// ---------------------------------------------------------------------------
// Output MLP: 64 -> 64 (elu) -> 32 (elu) -> 8. 4 waves/block, shfl-based.
// ---------------------------------------------------------------------------
__global__ __launch_bounds__(256) void out_mlp_kernel(
    const float* __restrict__ h, const float* __restrict__ W1,
    const float* __restrict__ b1, const float* __restrict__ W2,
    const float* __restrict__ b2, const float* __restrict__ W3,
    const float* __restrict__ b3, float* __restrict__ out, int n_nodes) {
    const int wid = threadIdx.x >> 6;
    const int lane = threadIdx.x & 63;
    const int n = blockIdx.x * 4 + wid;
    if (n >= n_nodes) return;
    const float hv = h[(size_t)n * 64 + lane];
    float a = b1[lane];
#pragma unroll
    for (int k = 0; k < 64; ++k) a += __shfl(hv, k) * W1[k * 64 + lane];
    const float o1 = elu_f(a);
    const int c2 = lane & 31;
    float a2 = b2[c2];
#pragma unroll
    for (int k = 0; k < 64; ++k) a2 += __shfl(o1, k) * W2[k * 32 + c2];
    const float o2 = elu_f(a2);
    const int c3 = lane & 7;
    float a3 = b3[c3];
#pragma unroll
    for (int k = 0; k < 32; ++k) a3 += __shfl(o2, k) * W3[k * 8 + c3];
    if (lane < 8) out[(size_t)n * 8 + lane] = a3;
}

// ---------------------------------------------------------------------------
extern "C" void kernel_launch(void* const* d_in, const int* in_sizes, int n_in,
                              void* d_out, int out_size, void* d_ws, size_t ws_size,
                              hipStream_t stream) {
    const float* x     = (const float*)d_in[0];
    const int*   ei    = (const int*)d_in[1];
    const float* Wenc1 = (const float*)d_in[2];
    const float* benc1 = (const float*)d_in[3];
    const float* Wenc2 = (const float*)d_in[4];
    const float* benc2 = (const float*)d_in[5];
    const float* Wg[3]  = {(const float*)d_in[6],  (const float*)d_in[10], (const float*)d_in[14]};
    const float* as_[3] = {(const float*)d_in[7],  (const float*)d_in[11], (const float*)d_in[15]};
    const float* ad_[3] = {(const float*)d_in[8],  (const float*)d_in[12], (const float*)d_in[16]};
    const float* bg[3]  = {(const float*)d_in[9],  (const float*)d_in[13], (const float*)d_in[17]};
    const float* Wo1 = (const float*)d_in[18];
    const float* bo1 = (const float*)d_in[19];
    const float* Wo2 = (const float*)d_in[20];
    const float* bo2 = (const float*)d_in[21];
    const float* Wo3 = (const float*)d_in[22];
    const float* bo3 = (const float*)d_in[23];

    const int N = in_sizes[0] / 8;
    const int E = in_sizes[1] / 2;
    const int Etot = E + N;
    const int nblk = (N + SCAN_B - 1) / SCAN_B;

    float* buf0 = (float*)d_ws;                  // N*64
    float* buf1 = buf0 + (size_t)N * 64;         // N*64
    float* g    = buf1 + (size_t)N * 64;         // N*256 (per-head aggregates)
    float* asrc = g + (size_t)N * 256;           // N*4
    float* adst = asrc + (size_t)N * 4;          // N*4
    int* rowptr = (int*)(adst + (size_t)N * 4);  // N+1 (+pad)
    int* cursor = rowptr + (N + 2);              // N
    int* cnt    = cursor + N;                    // N
    int* incl   = cnt + N;                       // N
    int* bsum   = incl + N;                      // 256
    int* boff   = bsum + 256;                    // 256
    int* flag   = boff + 256;                    // 1 (+pad)
    int* col    = flag + 2;                      // Etot

    // ---- CSR build ----
    zero_detect_kernel<<<(N + 255) / 256, 256, 0, stream>>>(ei, cnt, flag, N);
    count_kernel<<<(Etot + 255) / 256, 256, 0, stream>>>(ei, flag, E, Etot, cnt);
    scan1_kernel<<<nblk, SCAN_B, 0, stream>>>(cnt, incl, bsum, N);
    scan2_kernel<<<1, 256, 0, stream>>>(bsum, boff, nblk);
    scan3_kernel<<<nblk, SCAN_B, 0, stream>>>(incl, boff, cnt, rowptr, cursor, N);
    fill_kernel<<<(Etot + 255) / 256, 256, 0, stream>>>(ei, flag, E, Etot, cursor, col);

    // ---- encoder ----
    encoder_kernel<<<(N + 255) / 256, 256, 0, stream>>>(x, Wenc1, benc1, Wenc2, benc2, buf0, N);

    // ---- 3 GAT layers (aggregate-then-project; ping-pong buf0/buf1) ----
    float* bin = buf0;
    float* bout = buf1;
    for (int l = 0; l < 3; ++l) {
        gat_dots_kernel<<<(N + 31) / 32, 256, 0, stream>>>(bin, Wg[l], as_[l], ad_[l],
                                                           asrc, adst, N);
        gat_agg_kernel<<<(N + 3) / 4, 256, 0, stream>>>(bin, asrc, adst, rowptr, col,
                                                        g, N);
        gat_post_kernel<<<(N + 63) / 64, 256, 0, stream>>>(g, Wg[l], bg[l], bin,
                                                           bout, N);
        float* tmp = bin; bin = bout; bout = tmp;
    }

    // ---- output MLP (bin holds h3) ----
    out_mlp_kernel<<<(N + 3) / 4, 256, 0, stream>>>(bin, Wo1, bo1, Wo2, bo2, Wo3, bo3,
                                                    (float*)d_out, N);
}

// Round 5
// 370.196 us; speedup vs baseline: 1.2008x; 1.2008x over previous
//
#include <hip/hip_runtime.h>
#include <cstdint>
#include <cstddef>

#define NEG_SLOPE 0.2f

__device__ __forceinline__ float elu_f(float x) {
    return x > 0.f ? x : expm1f(x);
}

// ---------------------------------------------------------------------------
// Encoder: h0 = elu(elu(x @ W1 + b1) @ W2 + b2), x:[N,8] -> [N,64]
// ---------------------------------------------------------------------------
__global__ void encoder_kernel(const float* __restrict__ x,
                               const float* __restrict__ W1, const float* __restrict__ b1,
                               const float* __restrict__ W2, const float* __restrict__ b2,
                               float* __restrict__ h0, int n_nodes) {
    int i = blockIdx.x * blockDim.x + threadIdx.x;
    if (i >= n_nodes) return;
    const float4* xp = (const float4*)(x + (size_t)i * 8);
    float4 x0 = xp[0], x1 = xp[1];
    float xi[8] = {x0.x, x0.y, x0.z, x0.w, x1.x, x1.y, x1.z, x1.w};
    float h1[32];
#pragma unroll
    for (int j = 0; j < 32; ++j) {
        float a = b1[j];
#pragma unroll
        for (int k = 0; k < 8; ++k) a += xi[k] * W1[k * 32 + j];
        h1[j] = elu_f(a);
    }
    float* dst = h0 + (size_t)i * 64;
    for (int j = 0; j < 64; ++j) {
        float a = b2[j];
#pragma unroll
        for (int k = 0; k < 32; ++k) a += h1[k] * W2[k * 64 + j];
        dst[j] = elu_f(a);
    }
}

// ---------------------------------------------------------------------------
// CSR build (by destination), reused across all 3 GAT layers.
// ---------------------------------------------------------------------------
__global__ void zero_detect_kernel(const int* __restrict__ ei, int* __restrict__ cnt,
                                   int* __restrict__ flag, int n) {
    int i = blockIdx.x * blockDim.x + threadIdx.x;
    if (i < n) cnt[i] = 0;
    if (i == 0) {
        int acc = 0;
#pragma unroll
        for (int k = 0; k < 8; ++k) acc |= ei[2 * k + 1];
        flag[0] = (acc == 0) ? 1 : 0;  // high words all zero -> int64 layout
    }
}

__global__ void count_kernel(const int* __restrict__ ei, const int* __restrict__ flag,
                             int E, int Etot, int* __restrict__ cnt) {
    int e = blockIdx.x * blockDim.x + threadIdx.x;
    if (e >= Etot) return;
    int d;
    if (e < E) d = flag[0] ? ei[2 * (size_t)(E + e)] : ei[E + e];
    else       d = e - E;  // self loop
    atomicAdd(&cnt[d], 1);
}

#define SCAN_B 256
__global__ void scan1_kernel(const int* __restrict__ cnt, int* __restrict__ incl,
                             int* __restrict__ bsum, int n) {
    __shared__ int sd[SCAN_B];
    int t = threadIdx.x;
    int g = blockIdx.x * SCAN_B + t;
    int v = (g < n) ? cnt[g] : 0;
    sd[t] = v;
    __syncthreads();
    for (int off = 1; off < SCAN_B; off <<= 1) {
        int add = (t >= off) ? sd[t - off] : 0;
        __syncthreads();
        sd[t] += add;
        __syncthreads();
    }
    if (g < n) incl[g] = sd[t];
    if (t == SCAN_B - 1) bsum[blockIdx.x] = sd[SCAN_B - 1];
}

__global__ void scan2_kernel(const int* __restrict__ bsum, int* __restrict__ boff, int nb) {
    __shared__ int sd[256];
    int t = threadIdx.x;
    int v = (t < nb) ? bsum[t] : 0;
    sd[t] = v;
    __syncthreads();
    for (int off = 1; off < 256; off <<= 1) {
        int add = (t >= off) ? sd[t - off] : 0;
        __syncthreads();
        sd[t] += add;
        __syncthreads();
    }
    if (t < nb) boff[t] = sd[t] - v;  // exclusive block offset
}

__global__ void scan3_kernel(const int* __restrict__ incl, const int* __restrict__ boff,
                             const int* __restrict__ cnt, int* __restrict__ rowptr,
                             int* __restrict__ cursor, int n) {
    int i = blockIdx.x * SCAN_B + threadIdx.x;
    if (i >= n) return;
    int e = incl[i] + boff[blockIdx.x];
    rowptr[i + 1] = e;
    cursor[i] = e - cnt[i];
    if (i == 0) rowptr[0] = 0;
}

__global__ void fill_kernel(const int* __restrict__ ei, const int* __restrict__ flag,
                            int E, int Etot, int* __restrict__ cursor,
                            int* __restrict__ col) {
    int e = blockIdx.x * blockDim.x + threadIdx.x;
    if (e >= Etot) return;
    int s, d;
    if (e < E) {
        if (flag[0]) { s = ei[2 * (size_t)e]; d = ei[2 * (size_t)(E + e)]; }
        else         { s = ei[e];             d = ei[E + e]; }
    } else {
        s = d = e - E;
    }
    int pos = atomicAdd(&cursor[d], 1);
    col[pos] = s;
}

// ---------------------------------------------------------------------------
// Fold kernel (all 3 layers, one launch): vfold[l][k*8+j] =
//   sum_cc W_l[k,256]*att  (j<4: att_src head j ; j>=4: att_dst head j-4)
// ---------------------------------------------------------------------------
__global__ __launch_bounds__(256) void fold_all_kernel(
    const float* __restrict__ W0, const float* __restrict__ as0, const float* __restrict__ ad0,
    const float* __restrict__ W1, const float* __restrict__ as1, const float* __restrict__ ad1,
    const float* __restrict__ W2, const float* __restrict__ as2, const float* __restrict__ ad2,
    float* __restrict__ vfold) {
    const int l = blockIdx.x;
    const float* W  = (l == 0) ? W0  : (l == 1) ? W1  : W2;
    const float* as_ = (l == 0) ? as0 : (l == 1) ? as1 : as2;
    const float* ad_ = (l == 0) ? ad0 : (l == 1) ? ad1 : ad2;
    const int t = threadIdx.x;
#pragma unroll
    for (int u = 0; u < 2; ++u) {
        const int e = t * 2 + u;          // 0..511
        const int k = e >> 3, j = e & 7, h = j & 3;
        const float* av = (j < 4) ? as_ : ad_;
        float s = 0.f;
        const float* wr = W + k * 256 + h * 64;
        const float* ar = av + h * 64;
#pragma unroll 8
        for (int cc = 0; cc < 64; ++cc) s += wr[cc] * ar[cc];
        vfold[l * 512 + k * 8 + j] = s;
    }
}

// ---------------------------------------------------------------------------
// Attention dots: asrc[n,h] = bin[n] . vfold[:,h], adst likewise.
// Block = 32 nodes; lane handles (node, j): 16 float4 loads + 64 FMAs.
// ---------------------------------------------------------------------------
__global__ __launch_bounds__(256) void gat_dots_kernel(
    const float* __restrict__ bin, const float* __restrict__ vfold_l,
    float* __restrict__ asrc, float* __restrict__ adst, int n_nodes) {
    __shared__ float vsd[512];
    const int t = threadIdx.x;
    if (t < 128) *(float4*)(vsd + t * 4) = *(const float4*)(vfold_l + t * 4);
    __syncthreads();
    const int lane = t & 63, wv = t >> 6;
    const int n = blockIdx.x * 32 + wv * 8 + (lane >> 3);
    const int j = lane & 7, h = j & 3;
    if (n >= n_nodes) return;
    const float4* br4 = (const float4*)(bin + (size_t)n * 64);
    float a = 0.f;
#pragma unroll
    for (int kk = 0; kk < 16; ++kk) {
        const float4 v = br4[kk];
        a += v.x * vsd[(kk * 4 + 0) * 8 + j];
        a += v.y * vsd[(kk * 4 + 1) * 8 + j];
        a += v.z * vsd[(kk * 4 + 2) * 8 + j];
        a += v.w * vsd[(kk * 4 + 3) * 8 + j];
    }
    if (j < 4) asrc[n * 4 + h] = a;
    else       adst[n * 4 + h] = a;
}

// ---------------------------------------------------------------------------
// GAT aggregation: gathers RAW bin[src] (256B/edge). One wave per dst node.
// Writes per-head normalized sums g[n, h*64+k].
// ---------------------------------------------------------------------------
__global__ __launch_bounds__(256) void gat_agg_kernel(
    const float* __restrict__ bin, const float* __restrict__ asrc,
    const float* __restrict__ adst, const int* __restrict__ rowptr,
    const int* __restrict__ col, float* __restrict__ g, int n_nodes) {
    const int wid = threadIdx.x >> 6;
    const int lane = threadIdx.x & 63;
    const int n = blockIdx.x * 4 + wid;
    if (n >= n_nodes) return;
    const float4 ad4 = *(const float4*)(adst + (size_t)n * 4);
    const int start = rowptr[n], end = rowptr[n + 1];

    float acc0 = 0.f, acc1 = 0.f, acc2 = 0.f, acc3 = 0.f;
    float4 den4 = make_float4(0.f, 0.f, 0.f, 0.f);
    for (int base = start; base < end; base += 64) {
        const int cnt = min(64, end - base);
        int c = 0;
        float4 w4 = make_float4(0.f, 0.f, 0.f, 0.f);
        if (base + lane < end) {
            c = col[base + lane];
            const float4 av = *(const float4*)(asrc + (size_t)c * 4);
            float l0 = av.x + ad4.x; l0 = l0 > 0.f ? l0 : NEG_SLOPE * l0;
            float l1 = av.y + ad4.y; l1 = l1 > 0.f ? l1 : NEG_SLOPE * l1;
            float l2 = av.z + ad4.z; l2 = l2 > 0.f ? l2 : NEG_SLOPE * l2;
            float l3 = av.w + ad4.w; l3 = l3 > 0.f ? l3 : NEG_SLOPE * l3;
            w4.x = __expf(fminf(l0, 60.f));
            w4.y = __expf(fminf(l1, 60.f));
            w4.z = __expf(fminf(l2, 60.f));
            w4.w = __expf(fminf(l3, 60.f));
            den4.x += w4.x; den4.y += w4.y; den4.z += w4.z; den4.w += w4.w;
        }
        int j = 0;
        for (; j + 4 <= cnt; j += 4) {
            const int s0 = __shfl(c, j), s1 = __shfl(c, j + 1);
            const int s2 = __shfl(c, j + 2), s3 = __shfl(c, j + 3);
            const float h0 = bin[(size_t)s0 * 64 + lane];
            const float h1 = bin[(size_t)s1 * 64 + lane];
            const float h2 = bin[(size_t)s2 * 64 + lane];
            const float h3 = bin[(size_t)s3 * 64 + lane];
            acc0 += __shfl(w4.x, j) * h0 + __shfl(w4.x, j + 1) * h1
                  + __shfl(w4.x, j + 2) * h2 + __shfl(w4.x, j + 3) * h3;
            acc1 += __shfl(w4.y, j) * h0 + __shfl(w4.y, j + 1) * h1
                  + __shfl(w4.y, j + 2) * h2 + __shfl(w4.y, j + 3) * h3;
            acc2 += __shfl(w4.z, j) * h0 + __shfl(w4.z, j + 1) * h1
                  + __shfl(w4.z, j + 2) * h2 + __shfl(w4.z, j + 3) * h3;
            acc3 += __shfl(w4.w, j) * h0 + __shfl(w4.w, j + 1) * h1
                  + __shfl(w4.w, j + 2) * h2 + __shfl(w4.w, j + 3) * h3;
        }
        for (; j < cnt; ++j) {
            const int s = __shfl(c, j);
            const float hv = bin[(size_t)s * 64 + lane];
            acc0 += __shfl(w4.x, j) * hv;
            acc1 += __shfl(w4.y, j) * hv;
            acc2 += __shfl(w4.z, j) * hv;
            acc3 += __shfl(w4.w, j) * hv;
        }
    }
#pragma unroll
    for (int off = 1; off < 64; off <<= 1) {
        den4.x += __shfl_xor(den4.x, off);
        den4.y += __shfl_xor(den4.y, off);
        den4.z += __shfl_xor(den4.z, off);
        den4.w += __shfl_xor(den4.w, off);
    }
    float* gr = g + (size_t)n * 256 + lane;
    gr[0]   = acc0 / (den4.x + 1e-16f);
    gr[64]  = acc1 / (den4.y + 1e-16f);
    gr[128] = acc2 / (den4.z + 1e-16f);
    gr[192] = acc3 / (den4.w + 1e-16f);
}

// ---------------------------------------------------------------------------
// GAT post-projection: out[n,c] = 0.25 * sum_{h,k} g[n,h*64+k] * W[k,h*64+c]
//                               + bias[c] + bin[n,c]  (residual)
// Block = 64 nodes x 64 cols, K=256 in 2 slabs of 128; BOTH g and W slabbed:
// gS[64][132] (33.8 KB) + Wp[128][64] (32 KB) = 66.6 KB -> 2 blocks/CU.
// Micro-tile 2 nodes x 8 cols per thread (256 threads).
// ---------------------------------------------------------------------------
#define GSTR 132
__global__ __launch_bounds__(256) void gat_post_kernel(
    const float* __restrict__ g, const float* __restrict__ W,
    const float* __restrict__ bias, const float* __restrict__ xin,
    float* __restrict__ out, int n_nodes) {
    __shared__ float gS[64 * GSTR];  // 33,792 B
    __shared__ float Wp[128 * 64];   // 32,768 B
    const int t = threadIdx.x;
    const int n0 = blockIdx.x * 64;
    const int cg = t & 7;    // 8 col groups x 8 cols
    const int ng = t >> 3;   // 32 node groups x 2 nodes

    float acc[2][8];
#pragma unroll
    for (int i = 0; i < 2; ++i)
#pragma unroll
        for (int q = 0; q < 8; ++q) acc[i][q] = 0.f;

    for (int slab = 0; slab < 2; ++slab) {
        __syncthreads();  // protect previous slab's LDS reads
        // stage gS slab: 64 nodes x 128 k = 2048 float4, 8 per thread
#pragma unroll
        for (int j = 0; j < 8; ++j) {
            const int idx = j * 256 + t;       // float4 index
            const int nl = idx >> 5;           // node 0..63
            const int c4 = idx & 31;           // float4 within row (128 floats)
            float4 v = make_float4(0.f, 0.f, 0.f, 0.f);
            if (n0 + nl < n_nodes)
                v = *(const float4*)(g + (size_t)(n0 + nl) * 256 + slab * 128 + c4 * 4);
            *(float4*)(gS + nl * GSTR + c4 * 4) = v;
        }
        // stage Wp slab: Wp[kl][c] = W[kk, h*64+c], kap = slab*128+kl
#pragma unroll
        for (int j = 0; j < 8; ++j) {
            const int f4 = j * 256 + t;
            const int kl = f4 >> 4;
            const int kap = slab * 128 + kl;
            const int h = kap >> 6, kk = kap & 63;
            const int c = (f4 & 15) * 4;
            *(float4*)(Wp + kl * 64 + c) = *(const float4*)(W + kk * 256 + h * 64 + c);
        }
        __syncthreads();
#pragma unroll 4
        for (int kl = 0; kl < 128; ++kl) {
            const float a0 = gS[(ng * 2 + 0) * GSTR + kl];
            const float a1 = gS[(ng * 2 + 1) * GSTR + kl];
            const float4 b0 = *(const float4*)(Wp + kl * 64 + cg * 8);
            const float4 b1 = *(const float4*)(Wp + kl * 64 + cg * 8 + 4);
            acc[0][0] += a0 * b0.x; acc[0][1] += a0 * b0.y;
            acc[0][2] += a0 * b0.z; acc[0][3] += a0 * b0.w;
            acc[0][4] += a0 * b1.x; acc[0][5] += a0 * b1.y;
            acc[0][6] += a0 * b1.z; acc[0][7] += a0 * b1.w;
            acc[1][0] += a1 * b0.x; acc[1][1] += a1 * b0.y;
            acc[1][2] += a1 * b0.z; acc[1][3] += a1 * b0.w;
            acc[1][4] += a1 * b1.x; acc[1][5] += a1 * b1.y;
            acc[1][6] += a1 * b1.z; acc[1][7] += a1 * b1.w;
        }
    }

    const int c0 = cg * 8;
    const float4 bb0 = *(const float4*)(bias + c0);
    const float4 bb1 = *(const float4*)(bias + c0 + 4);
#pragma unroll
    for (int i = 0; i < 2; ++i) {
        const int n = n0 + ng * 2 + i;
        if (n >= n_nodes) continue;
        const float4 x0 = *(const float4*)(xin + (size_t)n * 64 + c0);
        const float4 x1 = *(const float4*)(xin + (size_t)n * 64 + c0 + 4);
        float4 o0, o1;
        o0.x = 0.25f * acc[i][0] + bb0.x + x0.x;
        o0.y = 0.25f * acc[i][1] + bb0.y + x0.y;
        o0.z = 0.25f * acc[i][2] + bb0.z + x0.z;
        o0.w = 0.25f * acc[i][3] + bb0.w + x0.w;
        o1.x = 0.25f * acc[i][4] + bb1.x + x1.x;
        o1.y = 0.25f * acc[i][5] + bb1.y + x1.y;
        o1.z = 0.25f * acc[i][6] + bb1.z + x1.z;
        o1.w = 0.25f * acc[i][7] + bb1.w + x1.w;
        *(float4*)(out + (size_t)n * 64 + c0) = o0;
        *(float4*)(out + (size_t)n * 64 + c0 + 4) = o1;
    }
}

// ---------------------------------------------------------------------------
// Output MLP: 64 -> 64 (elu) -> 32 (elu) -> 8. 4 waves/block, shfl-based.
// ---------------------------------------------------------------------------
__global__ __launch_bounds__(256) void out_mlp_kernel(
    const float* __restrict__ h, const float* __restrict__ W1,
    const float* __restrict__ b1, const float* __restrict__ W2,
    const float* __restrict__ b2, const float* __restrict__ W3,
    const float* __restrict__ b3, float* __restrict__ out, int n_nodes) {
    const int wid = threadIdx.x >> 6;
    const int lane = threadIdx.x & 63;
    const int n = blockIdx.x * 4 + wid;
    if (n >= n_nodes) return;
    const float hv = h[(size_t)n * 64 + lane];
    float a = b1[lane];
#pragma unroll
    for (int k = 0; k < 64; ++k) a += __shfl(hv, k) * W1[k * 64 + lane];
    const float o1 = elu_f(a);
    const int c2 = lane & 31;
    float a2 = b2[c2];
#pragma unroll
    for (int k = 0; k < 64; ++k) a2 += __shfl(o1, k) * W2[k * 32 + c2];
    const float o2 = elu_f(a2);
    const int c3 = lane & 7;
    float a3 = b3[c3];
#pragma unroll
    for (int k = 0; k < 32; ++k) a3 += __shfl(o2, k) * W3[k * 8 + c3];
    if (lane < 8) out[(size_t)n * 8 + lane] = a3;
}

// ---------------------------------------------------------------------------
extern "C" void kernel_launch(void* const* d_in, const int* in_sizes, int n_in,
                              void* d_out, int out_size, void* d_ws, size_t ws_size,
                              hipStream_t stream) {
    const float* x     = (const float*)d_in[0];
    const int*   ei    = (const int*)d_in[1];
    const float* Wenc1 = (const float*)d_in[2];
    const float* benc1 = (const float*)d_in[3];
    const float* Wenc2 = (const float*)d_in[4];
    const float* benc2 = (const float*)d_in[5];
    const float* Wg[3]  = {(const float*)d_in[6],  (const float*)d_in[10], (const float*)d_in[14]};
    const float* as_[3] = {(const float*)d_in[7],  (const float*)d_in[11], (const float*)d_in[15]};
    const float* ad_[3] = {(const float*)d_in[8],  (const float*)d_in[12], (const float*)d_in[16]};
    const float* bg[3]  = {(const float*)d_in[9],  (const float*)d_in[13], (const float*)d_in[17]};
    const float* Wo1 = (const float*)d_in[18];
    const float* bo1 = (const float*)d_in[19];
    const float* Wo2 = (const float*)d_in[20];
    const float* bo2 = (const float*)d_in[21];
    const float* Wo3 = (const float*)d_in[22];
    const float* bo3 = (const float*)d_in[23];

    const int N = in_sizes[0] / 8;
    const int E = in_sizes[1] / 2;
    const int Etot = E + N;
    const int nblk = (N + SCAN_B - 1) / SCAN_B;

    float* buf0  = (float*)d_ws;                  // N*64
    float* buf1  = buf0 + (size_t)N * 64;         // N*64
    float* g     = buf1 + (size_t)N * 64;         // N*256 (per-head aggregates)
    float* asrc  = g + (size_t)N * 256;           // N*4
    float* adst  = asrc + (size_t)N * 4;          // N*4
    float* vfold = adst + (size_t)N * 4;          // 3*512
    int* rowptr = (int*)(vfold + 3 * 512);        // N+1 (+pad)
    int* cursor = rowptr + (N + 2);               // N
    int* cnt    = cursor + N;                     // N
    int* incl   = cnt + N;                        // N
    int* bsum   = incl + N;                       // 256
    int* boff   = bsum + 256;                     // 256
    int* flag   = boff + 256;                     // 1 (+pad)
    int* col    = flag + 2;                       // Etot

    // ---- CSR build ----
    zero_detect_kernel<<<(N + 255) / 256, 256, 0, stream>>>(ei, cnt, flag, N);
    count_kernel<<<(Etot + 255) / 256, 256, 0, stream>>>(ei, flag, E, Etot, cnt);
    scan1_kernel<<<nblk, SCAN_B, 0, stream>>>(cnt, incl, bsum, N);
    scan2_kernel<<<1, 256, 0, stream>>>(bsum, boff, nblk);
    scan3_kernel<<<nblk, SCAN_B, 0, stream>>>(incl, boff, cnt, rowptr, cursor, N);
    fill_kernel<<<(Etot + 255) / 256, 256, 0, stream>>>(ei, flag, E, Etot, cursor, col);

    // ---- folded attention vectors for all 3 layers (one launch) ----
    fold_all_kernel<<<3, 256, 0, stream>>>(Wg[0], as_[0], ad_[0],
                                           Wg[1], as_[1], ad_[1],
                                           Wg[2], as_[2], ad_[2], vfold);

    // ---- encoder ----
    encoder_kernel<<<(N + 255) / 256, 256, 0, stream>>>(x, Wenc1, benc1, Wenc2, benc2, buf0, N);

    // ---- 3 GAT layers (aggregate-then-project; ping-pong buf0/buf1) ----
    float* bin = buf0;
    float* bout = buf1;
    for (int l = 0; l < 3; ++l) {
        gat_dots_kernel<<<(N + 31) / 32, 256, 0, stream>>>(bin, vfold + l * 512,
                                                           asrc, adst, N);
        gat_agg_kernel<<<(N + 3) / 4, 256, 0, stream>>>(bin, asrc, adst, rowptr, col,
                                                        g, N);
        gat_post_kernel<<<(N + 63) / 64, 256, 0, stream>>>(g, Wg[l], bg[l], bin,
                                                           bout, N);
        float* tmp = bin; bin = bout; bout = tmp;
    }

    // ---- output MLP (bin holds h3) ----
    out_mlp_kernel<<<(N + 3) / 4, 256, 0, stream>>>(bin, Wo1, bo1, Wo2, bo2, Wo3, bo3,
                                                    (float*)d_out, N);
}

// Round 6
// 339.227 us; speedup vs baseline: 1.3105x; 1.0913x over previous
//
#include <hip/hip_runtime.h>
#include <cstdint>
#include <cstddef>

#define NEG_SLOPE 0.2f

__device__ __forceinline__ float elu_f(float x) {
    return x > 0.f ? x : expm1f(x);
}

// ---------------------------------------------------------------------------
// Encoder + layer-0 attention dots:
// h0 = elu(elu(x @ W1 + b1) @ W2 + b2); asrc/adst[n,h] = h0[n] . vfold0[:,j]
// ---------------------------------------------------------------------------
__global__ __launch_bounds__(256) void encoder_kernel(
    const float* __restrict__ x,
    const float* __restrict__ W1, const float* __restrict__ b1,
    const float* __restrict__ W2, const float* __restrict__ b2,
    const float* __restrict__ vfold0,
    float* __restrict__ h0, float* __restrict__ asrc, float* __restrict__ adst,
    int n_nodes) {
    __shared__ float vsd[512];
    const int t = threadIdx.x;
    if (t < 128) *(float4*)(vsd + t * 4) = *(const float4*)(vfold0 + t * 4);
    __syncthreads();
    const int i = blockIdx.x * blockDim.x + t;
    if (i >= n_nodes) return;
    const float4* xp = (const float4*)(x + (size_t)i * 8);
    float4 x0 = xp[0], x1 = xp[1];
    float xi[8] = {x0.x, x0.y, x0.z, x0.w, x1.x, x1.y, x1.z, x1.w};
    float h1[32];
#pragma unroll
    for (int j = 0; j < 32; ++j) {
        float a = b1[j];
#pragma unroll
        for (int k = 0; k < 8; ++k) a += xi[k] * W1[k * 32 + j];
        h1[j] = elu_f(a);
    }
    float* dst = h0 + (size_t)i * 64;
    float adot[8];
#pragma unroll
    for (int jj = 0; jj < 8; ++jj) adot[jj] = 0.f;
    for (int j = 0; j < 64; ++j) {
        float a = b2[j];
#pragma unroll
        for (int k = 0; k < 32; ++k) a += h1[k] * W2[k * 64 + j];
        a = elu_f(a);
        dst[j] = a;
#pragma unroll
        for (int jj = 0; jj < 8; ++jj) adot[jj] += a * vsd[j * 8 + jj];
    }
#pragma unroll
    for (int h = 0; h < 4; ++h) {
        asrc[i * 4 + h] = adot[h];
        adst[i * 4 + h] = adot[4 + h];
    }
}

// ---------------------------------------------------------------------------
// CSR build (by destination), reused across all 3 GAT layers.
// ---------------------------------------------------------------------------
__global__ void zero_detect_kernel(const int* __restrict__ ei, int* __restrict__ cnt,
                                   int* __restrict__ flag, int n) {
    int i = blockIdx.x * blockDim.x + threadIdx.x;
    if (i < n) cnt[i] = 0;
    if (i == 0) {
        int acc = 0;
#pragma unroll
        for (int k = 0; k < 8; ++k) acc |= ei[2 * k + 1];
        flag[0] = (acc == 0) ? 1 : 0;  // high words all zero -> int64 layout
    }
}

__global__ void count_kernel(const int* __restrict__ ei, const int* __restrict__ flag,
                             int E, int Etot, int* __restrict__ cnt) {
    int e = blockIdx.x * blockDim.x + threadIdx.x;
    if (e >= Etot) return;
    int d;
    if (e < E) d = flag[0] ? ei[2 * (size_t)(E + e)] : ei[E + e];
    else       d = e - E;  // self loop
    atomicAdd(&cnt[d], 1);
}

#define SCAN_B 256
__global__ void scan1_kernel(const int* __restrict__ cnt, int* __restrict__ incl,
                             int* __restrict__ bsum, int n) {
    __shared__ int sd[SCAN_B];
    int t = threadIdx.x;
    int g = blockIdx.x * SCAN_B + t;
    int v = (g < n) ? cnt[g] : 0;
    sd[t] = v;
    __syncthreads();
    for (int off = 1; off < SCAN_B; off <<= 1) {
        int add = (t >= off) ? sd[t - off] : 0;
        __syncthreads();
        sd[t] += add;
        __syncthreads();
    }
    if (g < n) incl[g] = sd[t];
    if (t == SCAN_B - 1) bsum[blockIdx.x] = sd[SCAN_B - 1];
}

__global__ void scan2_kernel(const int* __restrict__ bsum, int* __restrict__ boff, int nb) {
    __shared__ int sd[256];
    int t = threadIdx.x;
    int v = (t < nb) ? bsum[t] : 0;
    sd[t] = v;
    __syncthreads();
    for (int off = 1; off < 256; off <<= 1) {
        int add = (t >= off) ? sd[t - off] : 0;
        __syncthreads();
        sd[t] += add;
        __syncthreads();
    }
    if (t < nb) boff[t] = sd[t] - v;  // exclusive block offset
}

__global__ void scan3_kernel(const int* __restrict__ incl, const int* __restrict__ boff,
                             const int* __restrict__ cnt, int* __restrict__ rowptr,
                             int* __restrict__ cursor, int n) {
    int i = blockIdx.x * SCAN_B + threadIdx.x;
    if (i >= n) return;
    int e = incl[i] + boff[blockIdx.x];
    rowptr[i + 1] = e;
    cursor[i] = e - cnt[i];
    if (i == 0) rowptr[0] = 0;
}

__global__ void fill_kernel(const int* __restrict__ ei, const int* __restrict__ flag,
                            int E, int Etot, int* __restrict__ cursor,
                            int* __restrict__ col) {
    int e = blockIdx.x * blockDim.x + threadIdx.x;
    if (e >= Etot) return;
    int s, d;
    if (e < E) {
        if (flag[0]) { s = ei[2 * (size_t)e]; d = ei[2 * (size_t)(E + e)]; }
        else         { s = ei[e];             d = ei[E + e]; }
    } else {
        s = d = e - E;
    }
    int pos = atomicAdd(&cursor[d], 1);
    col[pos] = s;
}

// ---------------------------------------------------------------------------
// Fold kernel (all 3 layers): vfold[l][k*8+j] = sum_cc W_l[k, h*64+cc]*att[h,cc]
// (j<4: att_src head j ; j>=4: att_dst head j-4)
// ---------------------------------------------------------------------------
__global__ __launch_bounds__(256) void fold_all_kernel(
    const float* __restrict__ W0, const float* __restrict__ as0, const float* __restrict__ ad0,
    const float* __restrict__ W1, const float* __restrict__ as1, const float* __restrict__ ad1,
    const float* __restrict__ W2, const float* __restrict__ as2, const float* __restrict__ ad2,
    float* __restrict__ vfold) {
    const int l = blockIdx.x;
    const float* W   = (l == 0) ? W0  : (l == 1) ? W1  : W2;
    const float* as_ = (l == 0) ? as0 : (l == 1) ? as1 : as2;
    const float* ad_ = (l == 0) ? ad0 : (l == 1) ? ad1 : ad2;
    const int t = threadIdx.x;
#pragma unroll
    for (int u = 0; u < 2; ++u) {
        const int e = t * 2 + u;          // 0..511
        const int k = e >> 3, j = e & 7, h = j & 3;
        const float* av = (j < 4) ? as_ : ad_;
        float s = 0.f;
        const float* wr = W + k * 256 + h * 64;
        const float* ar = av + h * 64;
#pragma unroll 8
        for (int cc = 0; cc < 64; ++cc) s += wr[cc] * ar[cc];
        vfold[l * 512 + k * 8 + j] = s;
    }
}

// ---------------------------------------------------------------------------
// GAT aggregation v4: one 16-lane group per dst node (4 nodes/wave, 16/block).
// Lane q covers channels 4q..4q+3 (float4 gather: group reads 256B/edge).
// Chunk of 16 edges: lane q prefetches col + 4 exp weights; 4-unrolled serial
// loop broadcasts within the group (shfl width 16). acc[4 heads][4 ch]/lane.
// Writes per-head normalized sums g[n, h*64+c].
// ---------------------------------------------------------------------------
__global__ __launch_bounds__(256) void gat_agg_kernel(
    const float* __restrict__ bin, const float* __restrict__ asrc,
    const float* __restrict__ adst, const int* __restrict__ rowptr,
    const int* __restrict__ col, float* __restrict__ g, int n_nodes) {
    const int grp = threadIdx.x >> 4;
    const int q = threadIdx.x & 15;
    const int n = blockIdx.x * 16 + grp;
    if (n >= n_nodes) return;
    const float4 ad4 = *(const float4*)(adst + (size_t)n * 4);
    const int start = rowptr[n], end = rowptr[n + 1];

    float acc[4][4];
#pragma unroll
    for (int h = 0; h < 4; ++h)
#pragma unroll
        for (int z = 0; z < 4; ++z) acc[h][z] = 0.f;
    float4 den4 = make_float4(0.f, 0.f, 0.f, 0.f);

    for (int base = start; base < end; base += 16) {
        const int cnt = min(16, end - base);
        int c = 0;
        float4 w4 = make_float4(0.f, 0.f, 0.f, 0.f);
        if (base + q < end) {
            c = col[base + q];
            const float4 av = *(const float4*)(asrc + (size_t)c * 4);
            float l0 = av.x + ad4.x; l0 = l0 > 0.f ? l0 : NEG_SLOPE * l0;
            float l1 = av.y + ad4.y; l1 = l1 > 0.f ? l1 : NEG_SLOPE * l1;
            float l2 = av.z + ad4.z; l2 = l2 > 0.f ? l2 : NEG_SLOPE * l2;
            float l3 = av.w + ad4.w; l3 = l3 > 0.f ? l3 : NEG_SLOPE * l3;
            w4.x = __expf(fminf(l0, 60.f));
            w4.y = __expf(fminf(l1, 60.f));
            w4.z = __expf(fminf(l2, 60.f));
            w4.w = __expf(fminf(l3, 60.f));
            den4.x += w4.x; den4.y += w4.y; den4.z += w4.z; den4.w += w4.w;
        }
        int j = 0;
        for (; j + 4 <= cnt; j += 4) {
#pragma unroll
            for (int u = 0; u < 4; ++u) {
                const int s = __shfl(c, j + u, 16);
                const float4 hv = *(const float4*)(bin + (size_t)s * 64 + q * 4);
                const float wx = __shfl(w4.x, j + u, 16);
                const float wy = __shfl(w4.y, j + u, 16);
                const float wz = __shfl(w4.z, j + u, 16);
                const float ww = __shfl(w4.w, j + u, 16);
                acc[0][0] += wx * hv.x; acc[0][1] += wx * hv.y;
                acc[0][2] += wx * hv.z; acc[0][3] += wx * hv.w;
                acc[1][0] += wy * hv.x; acc[1][1] += wy * hv.y;
                acc[1][2] += wy * hv.z; acc[1][3] += wy * hv.w;
                acc[2][0] += wz * hv.x; acc[2][1] += wz * hv.y;
                acc[2][2] += wz * hv.z; acc[2][3] += wz * hv.w;
                acc[3][0] += ww * hv.x; acc[3][1] += ww * hv.y;
                acc[3][2] += ww * hv.z; acc[3][3] += ww * hv.w;
            }
        }
        for (; j < cnt; ++j) {
            const int s = __shfl(c, j, 16);
            const float4 hv = *(const float4*)(bin + (size_t)s * 64 + q * 4);
            const float wx = __shfl(w4.x, j, 16);
            const float wy = __shfl(w4.y, j, 16);
            const float wz = __shfl(w4.z, j, 16);
            const float ww = __shfl(w4.w, j, 16);
            acc[0][0] += wx * hv.x; acc[0][1] += wx * hv.y;
            acc[0][2] += wx * hv.z; acc[0][3] += wx * hv.w;
            acc[1][0] += wy * hv.x; acc[1][1] += wy * hv.y;
            acc[1][2] += wy * hv.z; acc[1][3] += wy * hv.w;
            acc[2][0] += wz * hv.x; acc[2][1] += wz * hv.y;
            acc[2][2] += wz * hv.z; acc[2][3] += wz * hv.w;
            acc[3][0] += ww * hv.x; acc[3][1] += ww * hv.y;
            acc[3][2] += ww * hv.z; acc[3][3] += ww * hv.w;
        }
    }
    // reduce den across the 16-lane group
#pragma unroll
    for (int off = 1; off < 16; off <<= 1) {
        den4.x += __shfl_xor(den4.x, off, 16);
        den4.y += __shfl_xor(den4.y, off, 16);
        den4.z += __shfl_xor(den4.z, off, 16);
        den4.w += __shfl_xor(den4.w, off, 16);
    }
    const float i0 = 1.f / (den4.x + 1e-16f);
    const float i1 = 1.f / (den4.y + 1e-16f);
    const float i2 = 1.f / (den4.z + 1e-16f);
    const float i3 = 1.f / (den4.w + 1e-16f);
    float* gr = g + (size_t)n * 256 + q * 4;
    *(float4*)(gr +   0) = make_float4(acc[0][0]*i0, acc[0][1]*i0, acc[0][2]*i0, acc[0][3]*i0);
    *(float4*)(gr +  64) = make_float4(acc[1][0]*i1, acc[1][1]*i1, acc[1][2]*i1, acc[1][3]*i1);
    *(float4*)(gr + 128) = make_float4(acc[2][0]*i2, acc[2][1]*i2, acc[2][2]*i2, acc[2][3]*i2);
    *(float4*)(gr + 192) = make_float4(acc[3][0]*i3, acc[3][1]*i3, acc[3][2]*i3, acc[3][3]*i3);
}

// ---------------------------------------------------------------------------
// GAT post-projection (+ fused next-layer dots):
// out[n,c] = 0.25 * sum_{h,k} g[n,h*64+k] * W[k,h*64+c] + bias[c] + bin[n,c]
// If has_next: asrc/adst[n,h] = out[n] . vfold_next[:,j] (shfl-reduced).
// Block = 64 nodes x 64 cols, K=256 in 2 slabs of 128 (g and W both slabbed).
// ---------------------------------------------------------------------------
#define GSTR 132
__global__ __launch_bounds__(256) void gat_post_kernel(
    const float* __restrict__ g, const float* __restrict__ W,
    const float* __restrict__ bias, const float* __restrict__ xin,
    const float* __restrict__ vfold_next, int has_next,
    float* __restrict__ out, float* __restrict__ asrc, float* __restrict__ adst,
    int n_nodes) {
    __shared__ float gS[64 * GSTR];  // 33,792 B
    __shared__ float Wp[128 * 64];   // 32,768 B
    __shared__ float vN[512];        //  2,048 B
    const int t = threadIdx.x;
    const int n0 = blockIdx.x * 64;
    const int cg = t & 7;    // 8 col groups x 8 cols
    const int ng = t >> 3;   // 32 node groups x 2 nodes

    if (has_next && t < 128) *(float4*)(vN + t * 4) = *(const float4*)(vfold_next + t * 4);

    float acc[2][8];
#pragma unroll
    for (int i = 0; i < 2; ++i)
#pragma unroll
        for (int qq = 0; qq < 8; ++qq) acc[i][qq] = 0.f;

    for (int slab = 0; slab < 2; ++slab) {
        __syncthreads();  // protect previous slab's LDS reads (and vN stage)
        // stage gS slab: 64 nodes x 128 k = 2048 float4, 8 per thread
#pragma unroll
        for (int j = 0; j < 8; ++j) {
            const int idx = j * 256 + t;
            const int nl = idx >> 5;
            const int c4 = idx & 31;
            float4 v = make_float4(0.f, 0.f, 0.f, 0.f);
            if (n0 + nl < n_nodes)
                v = *(const float4*)(g + (size_t)(n0 + nl) * 256 + slab * 128 + c4 * 4);
            *(float4*)(gS + nl * GSTR + c4 * 4) = v;
        }
        // stage Wp slab: Wp[kl][c] = W[kk, h*64+c], kap = slab*128+kl
#pragma unroll
        for (int j = 0; j < 8; ++j) {
            const int f4 = j * 256 + t;
            const int kl = f4 >> 4;
            const int kap = slab * 128 + kl;
            const int h = kap >> 6, kk = kap & 63;
            const int c = (f4 & 15) * 4;
            *(float4*)(Wp + kl * 64 + c) = *(const float4*)(W + kk * 256 + h * 64 + c);
        }
        __syncthreads();
#pragma unroll 4
        for (int kl = 0; kl < 128; ++kl) {
            const float a0 = gS[(ng * 2 + 0) * GSTR + kl];
            const float a1 = gS[(ng * 2 + 1) * GSTR + kl];
            const float4 b0 = *(const float4*)(Wp + kl * 64 + cg * 8);
            const float4 b1 = *(const float4*)(Wp + kl * 64 + cg * 8 + 4);
            acc[0][0] += a0 * b0.x; acc[0][1] += a0 * b0.y;
            acc[0][2] += a0 * b0.z; acc[0][3] += a0 * b0.w;
            acc[0][4] += a0 * b1.x; acc[0][5] += a0 * b1.y;
            acc[0][6] += a0 * b1.z; acc[0][7] += a0 * b1.w;
            acc[1][0] += a1 * b0.x; acc[1][1] += a1 * b0.y;
            acc[1][2] += a1 * b0.z; acc[1][3] += a1 * b0.w;
            acc[1][4] += a1 * b1.x; acc[1][5] += a1 * b1.y;
            acc[1][6] += a1 * b1.z; acc[1][7] += a1 * b1.w;
        }
    }

    const int c0 = cg * 8;
    const float4 bb0 = *(const float4*)(bias + c0);
    const float4 bb1 = *(const float4*)(bias + c0 + 4);
    float o[2][8];
#pragma unroll
    for (int i = 0; i < 2; ++i) {
        const int n = n0 + ng * 2 + i;
        if (n < n_nodes) {
            const float4 x0 = *(const float4*)(xin + (size_t)n * 64 + c0);
            const float4 x1 = *(const float4*)(xin + (size_t)n * 64 + c0 + 4);
            o[i][0] = 0.25f * acc[i][0] + bb0.x + x0.x;
            o[i][1] = 0.25f * acc[i][1] + bb0.y + x0.y;
            o[i][2] = 0.25f * acc[i][2] + bb0.z + x0.z;
            o[i][3] = 0.25f * acc[i][3] + bb0.w + x0.w;
            o[i][4] = 0.25f * acc[i][4] + bb1.x + x1.x;
            o[i][5] = 0.25f * acc[i][5] + bb1.y + x1.y;
            o[i][6] = 0.25f * acc[i][6] + bb1.z + x1.z;
            o[i][7] = 0.25f * acc[i][7] + bb1.w + x1.w;
            *(float4*)(out + (size_t)n * 64 + c0) =
                make_float4(o[i][0], o[i][1], o[i][2], o[i][3]);
            *(float4*)(out + (size_t)n * 64 + c0 + 4) =
                make_float4(o[i][4], o[i][5], o[i][6], o[i][7]);
        } else {
#pragma unroll
            for (int qq = 0; qq < 8; ++qq) o[i][qq] = 0.f;
        }
    }

    if (has_next) {
        // dots: pj[i][j] = sum over this thread's 8 cols of o * vN[(c0+c)*8+j]
        float pj[2][8];
#pragma unroll
        for (int i = 0; i < 2; ++i)
#pragma unroll
            for (int jj = 0; jj < 8; ++jj) pj[i][jj] = 0.f;
#pragma unroll
        for (int cidx = 0; cidx < 8; ++cidx) {
#pragma unroll
            for (int jj = 0; jj < 8; ++jj) {
                const float vv = vN[(c0 + cidx) * 8 + jj];
                pj[0][jj] += o[0][cidx] * vv;
                pj[1][jj] += o[1][cidx] * vv;
            }
        }
        // reduce across the 8 cg lanes (offsets 1,2,4 within wave)
#pragma unroll
        for (int off = 1; off < 8; off <<= 1) {
#pragma unroll
            for (int i = 0; i < 2; ++i)
#pragma unroll
                for (int jj = 0; jj < 8; ++jj)
                    pj[i][jj] += __shfl_xor(pj[i][jj], off);
        }
        if (cg == 0) {
#pragma unroll
            for (int i = 0; i < 2; ++i) {
                const int n = n0 + ng * 2 + i;
                if (n < n_nodes) {
#pragma unroll
                    for (int h = 0; h < 4; ++h) {
                        asrc[n * 4 + h] = pj[i][h];
                        adst[n * 4 + h] = pj[i][4 + h];
                    }
                }
            }
        }
    }
}

// ---------------------------------------------------------------------------
// Output MLP: 64 -> 64 (elu) -> 32 (elu) -> 8. 4 waves/block, shfl-based.
// ---------------------------------------------------------------------------
__global__ __launch_bounds__(256) void out_mlp_kernel(
    const float* __restrict__ h, const float* __restrict__ W1,
    const float* __restrict__ b1, const float* __restrict__ W2,
    const float* __restrict__ b2, const float* __restrict__ W3,
    const float* __restrict__ b3, float* __restrict__ out, int n_nodes) {
    const int wid = threadIdx.x >> 6;
    const int lane = threadIdx.x & 63;
    const int n = blockIdx.x * 4 + wid;
    if (n >= n_nodes) return;
    const float hv = h[(size_t)n * 64 + lane];
    float a = b1[lane];
#pragma unroll
    for (int k = 0; k < 64; ++k) a += __shfl(hv, k) * W1[k * 64 + lane];
    const float o1 = elu_f(a);
    const int c2 = lane & 31;
    float a2 = b2[c2];
#pragma unroll
    for (int k = 0; k < 64; ++k) a2 += __shfl(o1, k) * W2[k * 32 + c2];
    const float o2 = elu_f(a2);
    const int c3 = lane & 7;
    float a3 = b3[c3];
#pragma unroll
    for (int k = 0; k < 32; ++k) a3 += __shfl(o2, k) * W3[k * 8 + c3];
    if (lane < 8) out[(size_t)n * 8 + lane] = a3;
}

// ---------------------------------------------------------------------------
extern "C" void kernel_launch(void* const* d_in, const int* in_sizes, int n_in,
                              void* d_out, int out_size, void* d_ws, size_t ws_size,
                              hipStream_t stream) {
    const float* x     = (const float*)d_in[0];
    const int*   ei    = (const int*)d_in[1];
    const float* Wenc1 = (const float*)d_in[2];
    const float* benc1 = (const float*)d_in[3];
    const float* Wenc2 = (const float*)d_in[4];
    const float* benc2 = (const float*)d_in[5];
    const float* Wg[3]  = {(const float*)d_in[6],  (const float*)d_in[10], (const float*)d_in[14]};
    const float* as_[3] = {(const float*)d_in[7],  (const float*)d_in[11], (const float*)d_in[15]};
    const float* ad_[3] = {(const float*)d_in[8],  (const float*)d_in[12], (const float*)d_in[16]};
    const float* bg[3]  = {(const float*)d_in[9],  (const float*)d_in[13], (const float*)d_in[17]};
    const float* Wo1 = (const float*)d_in[18];
    const float* bo1 = (const float*)d_in[19];
    const float* Wo2 = (const float*)d_in[20];
    const float* bo2 = (const float*)d_in[21];
    const float* Wo3 = (const float*)d_in[22];
    const float* bo3 = (const float*)d_in[23];

    const int N = in_sizes[0] / 8;
    const int E = in_sizes[1] / 2;
    const int Etot = E + N;
    const int nblk = (N + SCAN_B - 1) / SCAN_B;

    float* buf0  = (float*)d_ws;                  // N*64
    float* buf1  = buf0 + (size_t)N * 64;         // N*64
    float* g     = buf1 + (size_t)N * 64;         // N*256 (per-head aggregates)
    float* asrc  = g + (size_t)N * 256;           // N*4
    float* adst  = asrc + (size_t)N * 4;          // N*4
    float* vfold = adst + (size_t)N * 4;          // 3*512
    int* rowptr = (int*)(vfold + 3 * 512);        // N+1 (+pad)
    int* cursor = rowptr + (N + 2);               // N
    int* cnt    = cursor + N;                     // N
    int* incl   = cnt + N;                        // N
    int* bsum   = incl + N;                       // 256
    int* boff   = bsum + 256;                     // 256
    int* flag   = boff + 256;                     // 1 (+pad)
    int* col    = flag + 2;                       // Etot

    // ---- CSR build ----
    zero_detect_kernel<<<(N + 255) / 256, 256, 0, stream>>>(ei, cnt, flag, N);
    count_kernel<<<(Etot + 255) / 256, 256, 0, stream>>>(ei, flag, E, Etot, cnt);
    scan1_kernel<<<nblk, SCAN_B, 0, stream>>>(cnt, incl, bsum, N);
    scan2_kernel<<<1, 256, 0, stream>>>(bsum, boff, nblk);
    scan3_kernel<<<nblk, SCAN_B, 0, stream>>>(incl, boff, cnt, rowptr, cursor, N);
    fill_kernel<<<(Etot + 255) / 256, 256, 0, stream>>>(ei, flag, E, Etot, cursor, col);

    // ---- folded attention vectors for all 3 layers ----
    fold_all_kernel<<<3, 256, 0, stream>>>(Wg[0], as_[0], ad_[0],
                                           Wg[1], as_[1], ad_[1],
                                           Wg[2], as_[2], ad_[2], vfold);

    // ---- encoder (+ layer-0 dots) ----
    encoder_kernel<<<(N + 255) / 256, 256, 0, stream>>>(x, Wenc1, benc1, Wenc2, benc2,
                                                        vfold, buf0, asrc, adst, N);

    // ---- 3 GAT layers (aggregate-then-project; ping-pong buf0/buf1) ----
    float* bin = buf0;
    float* bout = buf1;
    for (int l = 0; l < 3; ++l) {
        gat_agg_kernel<<<(N + 15) / 16, 256, 0, stream>>>(bin, asrc, adst, rowptr, col,
                                                          g, N);
        const int has_next = (l < 2) ? 1 : 0;
        gat_post_kernel<<<(N + 63) / 64, 256, 0, stream>>>(
            g, Wg[l], bg[l], bin, vfold + (l + 1 < 3 ? (l + 1) * 512 : 0), has_next,
            bout, asrc, adst, N);
        float* tmp = bin; bin = bout; bout = tmp;
    }

    // ---- output MLP (bin holds h3) ----
    out_mlp_kernel<<<(N + 3) / 4, 256, 0, stream>>>(bin, Wo1, bo1, Wo2, bo2, Wo3, bo3,
                                                    (float*)d_out, N);
}

// Round 7
// 305.192 us; speedup vs baseline: 1.4566x; 1.1115x over previous
//
#include <hip/hip_runtime.h>
#include <cstdint>
#include <cstddef>

#define NEG_SLOPE 0.2f

__device__ __forceinline__ float elu_f(float x) {
    return x > 0.f ? x : expm1f(x);
}

// ---------------------------------------------------------------------------
// P0: zero cnt + ready, detect edge-index layout, compute folded attention
// vectors for all 3 layers. Blocks 0..78 zero; blocks 79..84 fold.
// vfold[l][k*8+j] = sum_cc W_l[k, h*64+cc]*att[h,cc] (j<4 src, j>=4 dst, h=j&3)
// ---------------------------------------------------------------------------
__global__ __launch_bounds__(256) void prep_kernel(
    const int* __restrict__ ei,
    const float* __restrict__ W0, const float* __restrict__ as0, const float* __restrict__ ad0,
    const float* __restrict__ W1, const float* __restrict__ as1, const float* __restrict__ ad1,
    const float* __restrict__ W2, const float* __restrict__ as2, const float* __restrict__ ad2,
    int* __restrict__ cnt, int* __restrict__ ready, int* __restrict__ flag,
    float* __restrict__ vfold, int n) {
    const int b = blockIdx.x, t = threadIdx.x;
    if (b < 79) {
        const int i = b * 256 + t;
        if (i < n) cnt[i] = 0;
        if (b == 0) {
            if (t < 128) ready[t] = 0;
            if (t == 0) {
                int acc = 0;
#pragma unroll
                for (int k = 0; k < 8; ++k) acc |= ei[2 * k + 1];
                flag[0] = (acc == 0) ? 1 : 0;
            }
        }
        return;
    }
    // fold: 1536 dot products across blocks 79..84
    const int e = (b - 79) * 256 + t;
    if (e >= 1536) return;
    const int l = e >> 9, rem = e & 511;
    const int k = rem >> 3, j = rem & 7, h = j & 3;
    const float* W   = (l == 0) ? W0  : (l == 1) ? W1  : W2;
    const float* as_ = (l == 0) ? as0 : (l == 1) ? as1 : as2;
    const float* ad_ = (l == 0) ? ad0 : (l == 1) ? ad1 : ad2;
    const float* av = (j < 4) ? as_ : ad_;
    const float* wr = W + k * 256 + h * 64;
    const float* ar = av + h * 64;
    float s = 0.f;
#pragma unroll 8
    for (int cc = 0; cc < 64; ++cc) s += wr[cc] * ar[cc];
    vfold[l * 512 + k * 8 + j] = s;
}

__global__ void count_kernel(const int* __restrict__ ei, const int* __restrict__ flag,
                             int E, int Etot, int* __restrict__ cnt) {
    int e = blockIdx.x * blockDim.x + threadIdx.x;
    if (e >= Etot) return;
    int d;
    if (e < E) d = flag[0] ? ei[2 * (size_t)(E + e)] : ei[E + e];
    else       d = e - E;  // self loop
    atomicAdd(&cnt[d], 1);
}

// ---------------------------------------------------------------------------
// One-pass scan with parallel lookback. 79 blocks, all co-resident (<=256 CU).
// ready[b] = chunk_total+1 published via atomicExch after local scan;
// every block spin-waits on all predecessors (single-word payload, no fence
// pairing needed beyond device-scope atomic visibility).
// ---------------------------------------------------------------------------
#define SCAN_B 256
__global__ __launch_bounds__(256) void scan_onepass_kernel(
    const int* __restrict__ cnt, int* __restrict__ ready,
    int* __restrict__ rowptr, int* __restrict__ cursor, int n) {
    __shared__ int sd[SCAN_B];
    __shared__ int sred[128];
    __shared__ int s_pref;
    const int b = blockIdx.x, t = threadIdx.x;
    const int g = b * SCAN_B + t;
    const int v = (g < n) ? cnt[g] : 0;
    sd[t] = v;
    __syncthreads();
    for (int off = 1; off < SCAN_B; off <<= 1) {
        int add = (t >= off) ? sd[t - off] : 0;
        __syncthreads();
        sd[t] += add;
        __syncthreads();
    }
    if (t == SCAN_B - 1) atomicExch(&ready[b], sd[SCAN_B - 1] + 1);
    // parallel lookback: sum predecessors' totals
    if (t < 128) {
        int pv = 0;
        if (t < b) {
            do { pv = atomicAdd(&ready[t], 0); __builtin_amdgcn_s_sleep(1); } while (pv == 0);
            pv -= 1;
        }
        sred[t] = pv;
    }
    __syncthreads();
    if (t == 0) {
        int s = 0;
#pragma unroll 8
        for (int i = 0; i < 128; ++i) s += sred[i];
        s_pref = s;
    }
    __syncthreads();
    const int pre = s_pref;
    if (g < n) {
        const int e = pre + sd[t];
        rowptr[g + 1] = e;
        cursor[g] = e - v;
        if (g == 0) rowptr[0] = 0;
    }
}

__global__ void fill_kernel(const int* __restrict__ ei, const int* __restrict__ flag,
                            int E, int Etot, int* __restrict__ cursor,
                            int* __restrict__ col) {
    int e = blockIdx.x * blockDim.x + threadIdx.x;
    if (e >= Etot) return;
    int s, d;
    if (e < E) {
        if (flag[0]) { s = ei[2 * (size_t)e]; d = ei[2 * (size_t)(E + e)]; }
        else         { s = ei[e];             d = ei[E + e]; }
    } else {
        s = d = e - E;
    }
    int pos = atomicAdd(&cursor[d], 1);
    col[pos] = s;
}

// ---------------------------------------------------------------------------
// Encoder + layer-0 attention dots.
// ---------------------------------------------------------------------------
__global__ __launch_bounds__(256) void encoder_kernel(
    const float* __restrict__ x,
    const float* __restrict__ W1, const float* __restrict__ b1,
    const float* __restrict__ W2, const float* __restrict__ b2,
    const float* __restrict__ vfold0,
    float* __restrict__ h0, float* __restrict__ asrc, float* __restrict__ adst,
    int n_nodes) {
    __shared__ float vsd[512];
    const int t = threadIdx.x;
    if (t < 128) *(float4*)(vsd + t * 4) = *(const float4*)(vfold0 + t * 4);
    __syncthreads();
    const int i = blockIdx.x * blockDim.x + t;
    if (i >= n_nodes) return;
    const float4* xp = (const float4*)(x + (size_t)i * 8);
    float4 x0 = xp[0], x1 = xp[1];
    float xi[8] = {x0.x, x0.y, x0.z, x0.w, x1.x, x1.y, x1.z, x1.w};
    float h1[32];
#pragma unroll
    for (int j = 0; j < 32; ++j) {
        float a = b1[j];
#pragma unroll
        for (int k = 0; k < 8; ++k) a += xi[k] * W1[k * 32 + j];
        h1[j] = elu_f(a);
    }
    float* dst = h0 + (size_t)i * 64;
    float adot[8];
#pragma unroll
    for (int jj = 0; jj < 8; ++jj) adot[jj] = 0.f;
    for (int j = 0; j < 64; ++j) {
        float a = b2[j];
#pragma unroll
        for (int k = 0; k < 32; ++k) a += h1[k] * W2[k * 64 + j];
        a = elu_f(a);
        dst[j] = a;
#pragma unroll
        for (int jj = 0; jj < 8; ++jj) adot[jj] += a * vsd[j * 8 + jj];
    }
#pragma unroll
    for (int h = 0; h < 4; ++h) {
        asrc[i * 4 + h] = adot[h];
        adst[i * 4 + h] = adot[4 + h];
    }
}

// ---------------------------------------------------------------------------
// GAT aggregation: one 16-lane group per dst node (4 nodes/wave, 16/block).
// ---------------------------------------------------------------------------
__global__ __launch_bounds__(256) void gat_agg_kernel(
    const float* __restrict__ bin, const float* __restrict__ asrc,
    const float* __restrict__ adst, const int* __restrict__ rowptr,
    const int* __restrict__ col, float* __restrict__ g, int n_nodes) {
    const int grp = threadIdx.x >> 4;
    const int q = threadIdx.x & 15;
    const int n = blockIdx.x * 16 + grp;
    if (n >= n_nodes) return;
    const float4 ad4 = *(const float4*)(adst + (size_t)n * 4);
    const int start = rowptr[n], end = rowptr[n + 1];

    float acc[4][4];
#pragma unroll
    for (int h = 0; h < 4; ++h)
#pragma unroll
        for (int z = 0; z < 4; ++z) acc[h][z] = 0.f;
    float4 den4 = make_float4(0.f, 0.f, 0.f, 0.f);

    for (int base = start; base < end; base += 16) {
        const int cnt = min(16, end - base);
        int c = 0;
        float4 w4 = make_float4(0.f, 0.f, 0.f, 0.f);
        if (base + q < end) {
            c = col[base + q];
            const float4 av = *(const float4*)(asrc + (size_t)c * 4);
            float l0 = av.x + ad4.x; l0 = l0 > 0.f ? l0 : NEG_SLOPE * l0;
            float l1 = av.y + ad4.y; l1 = l1 > 0.f ? l1 : NEG_SLOPE * l1;
            float l2 = av.z + ad4.z; l2 = l2 > 0.f ? l2 : NEG_SLOPE * l2;
            float l3 = av.w + ad4.w; l3 = l3 > 0.f ? l3 : NEG_SLOPE * l3;
            w4.x = __expf(fminf(l0, 60.f));
            w4.y = __expf(fminf(l1, 60.f));
            w4.z = __expf(fminf(l2, 60.f));
            w4.w = __expf(fminf(l3, 60.f));
            den4.x += w4.x; den4.y += w4.y; den4.z += w4.z; den4.w += w4.w;
        }
        int j = 0;
        for (; j + 4 <= cnt; j += 4) {
#pragma unroll
            for (int u = 0; u < 4; ++u) {
                const int s = __shfl(c, j + u, 16);
                const float4 hv = *(const float4*)(bin + (size_t)s * 64 + q * 4);
                const float wx = __shfl(w4.x, j + u, 16);
                const float wy = __shfl(w4.y, j + u, 16);
                const float wz = __shfl(w4.z, j + u, 16);
                const float ww = __shfl(w4.w, j + u, 16);
                acc[0][0] += wx * hv.x; acc[0][1] += wx * hv.y;
                acc[0][2] += wx * hv.z; acc[0][3] += wx * hv.w;
                acc[1][0] += wy * hv.x; acc[1][1] += wy * hv.y;
                acc[1][2] += wy * hv.z; acc[1][3] += wy * hv.w;
                acc[2][0] += wz * hv.x; acc[2][1] += wz * hv.y;
                acc[2][2] += wz * hv.z; acc[2][3] += wz * hv.w;
                acc[3][0] += ww * hv.x; acc[3][1] += ww * hv.y;
                acc[3][2] += ww * hv.z; acc[3][3] += ww * hv.w;
            }
        }
        for (; j < cnt; ++j) {
            const int s = __shfl(c, j, 16);
            const float4 hv = *(const float4*)(bin + (size_t)s * 64 + q * 4);
            const float wx = __shfl(w4.x, j, 16);
            const float wy = __shfl(w4.y, j, 16);
            const float wz = __shfl(w4.z, j, 16);
            const float ww = __shfl(w4.w, j, 16);
            acc[0][0] += wx * hv.x; acc[0][1] += wx * hv.y;
            acc[0][2] += wx * hv.z; acc[0][3] += wx * hv.w;
            acc[1][0] += wy * hv.x; acc[1][1] += wy * hv.y;
            acc[1][2] += wy * hv.z; acc[1][3] += wy * hv.w;
            acc[2][0] += wz * hv.x; acc[2][1] += wz * hv.y;
            acc[2][2] += wz * hv.z; acc[2][3] += wz * hv.w;
            acc[3][0] += ww * hv.x; acc[3][1] += ww * hv.y;
            acc[3][2] += ww * hv.z; acc[3][3] += ww * hv.w;
        }
    }
#pragma unroll
    for (int off = 1; off < 16; off <<= 1) {
        den4.x += __shfl_xor(den4.x, off, 16);
        den4.y += __shfl_xor(den4.y, off, 16);
        den4.z += __shfl_xor(den4.z, off, 16);
        den4.w += __shfl_xor(den4.w, off, 16);
    }
    const float i0 = 1.f / (den4.x + 1e-16f);
    const float i1 = 1.f / (den4.y + 1e-16f);
    const float i2 = 1.f / (den4.z + 1e-16f);
    const float i3 = 1.f / (den4.w + 1e-16f);
    float* gr = g + (size_t)n * 256 + q * 4;
    *(float4*)(gr +   0) = make_float4(acc[0][0]*i0, acc[0][1]*i0, acc[0][2]*i0, acc[0][3]*i0);
    *(float4*)(gr +  64) = make_float4(acc[1][0]*i1, acc[1][1]*i1, acc[1][2]*i1, acc[1][3]*i1);
    *(float4*)(gr + 128) = make_float4(acc[2][0]*i2, acc[2][1]*i2, acc[2][2]*i2, acc[2][3]*i2);
    *(float4*)(gr + 192) = make_float4(acc[3][0]*i3, acc[3][1]*i3, acc[3][2]*i3, acc[3][3]*i3);
}

// ---------------------------------------------------------------------------
// GAT post-projection. has_next=1: fused next-layer dots (writes asrc/adst).
// has_next=0 (last layer): fused output MLP 64->64->32->8 via LDS GEMMs,
// h3 never written to global; writes d_out directly.
// Block = 64 nodes x 64 cols; K=256 in 2 slabs (g and W both slabbed).
// LDS reuse map (fused MLP): gS cols 0..63 = h3 tile -> later o2S (cols 0..31);
// gS cols 64..127 = o1S; Wp = W1(4096)+W2(2048); vN = b1,b2,b3,W3.
// ---------------------------------------------------------------------------
#define GSTR 132
__global__ __launch_bounds__(256) void gat_post_kernel(
    const float* __restrict__ g, const float* __restrict__ W,
    const float* __restrict__ bias, const float* __restrict__ xin,
    const float* __restrict__ vfold_next, int has_next,
    float* __restrict__ out, float* __restrict__ asrc, float* __restrict__ adst,
    const float* __restrict__ Wm1, const float* __restrict__ bm1,
    const float* __restrict__ Wm2, const float* __restrict__ bm2,
    const float* __restrict__ Wm3, const float* __restrict__ bm3,
    float* __restrict__ mlp_out, int n_nodes) {
    __shared__ float gS[64 * GSTR];  // 33,792 B
    __shared__ float Wp[128 * 64];   // 32,768 B
    __shared__ float vN[512];        //  2,048 B
    const int t = threadIdx.x;
    const int n0 = blockIdx.x * 64;
    const int cg = t & 7;    // 8 col groups x 8 cols
    const int ng = t >> 3;   // 32 node groups x 2 nodes

    if (has_next && t < 128) *(float4*)(vN + t * 4) = *(const float4*)(vfold_next + t * 4);

    float acc[2][8];
#pragma unroll
    for (int i = 0; i < 2; ++i)
#pragma unroll
        for (int qq = 0; qq < 8; ++qq) acc[i][qq] = 0.f;

    for (int slab = 0; slab < 2; ++slab) {
        __syncthreads();
#pragma unroll
        for (int j = 0; j < 8; ++j) {
            const int idx = j * 256 + t;
            const int nl = idx >> 5;
            const int c4 = idx & 31;
            float4 v = make_float4(0.f, 0.f, 0.f, 0.f);
            if (n0 + nl < n_nodes)
                v = *(const float4*)(g + (size_t)(n0 + nl) * 256 + slab * 128 + c4 * 4);
            *(float4*)(gS + nl * GSTR + c4 * 4) = v;
        }
#pragma unroll
        for (int j = 0; j < 8; ++j) {
            const int f4 = j * 256 + t;
            const int kl = f4 >> 4;
            const int kap = slab * 128 + kl;
            const int h = kap >> 6, kk = kap & 63;
            const int c = (f4 & 15) * 4;
            *(float4*)(Wp + kl * 64 + c) = *(const float4*)(W + kk * 256 + h * 64 + c);
        }
        __syncthreads();
#pragma unroll 4
        for (int kl = 0; kl < 128; ++kl) {
            const float a0 = gS[(ng * 2 + 0) * GSTR + kl];
            const float a1 = gS[(ng * 2 + 1) * GSTR + kl];
            const float4 b0 = *(const float4*)(Wp + kl * 64 + cg * 8);
            const float4 b1 = *(const float4*)(Wp + kl * 64 + cg * 8 + 4);
            acc[0][0] += a0 * b0.x; acc[0][1] += a0 * b0.y;
            acc[0][2] += a0 * b0.z; acc[0][3] += a0 * b0.w;
            acc[0][4] += a0 * b1.x; acc[0][5] += a0 * b1.y;
            acc[0][6] += a0 * b1.z; acc[0][7] += a0 * b1.w;
            acc[1][0] += a1 * b0.x; acc[1][1] += a1 * b0.y;
            acc[1][2] += a1 * b0.z; acc[1][3] += a1 * b0.w;
            acc[1][4] += a1 * b1.x; acc[1][5] += a1 * b1.y;
            acc[1][6] += a1 * b1.z; acc[1][7] += a1 * b1.w;
        }
    }

    const int c0 = cg * 8;
    const float4 bb0 = *(const float4*)(bias + c0);
    const float4 bb1 = *(const float4*)(bias + c0 + 4);
    float o[2][8];
#pragma unroll
    for (int i = 0; i < 2; ++i) {
        const int n = n0 + ng * 2 + i;
        if (n < n_nodes) {
            const float4 x0 = *(const float4*)(xin + (size_t)n * 64 + c0);
            const float4 x1 = *(const float4*)(xin + (size_t)n * 64 + c0 + 4);
            o[i][0] = 0.25f * acc[i][0] + bb0.x + x0.x;
            o[i][1] = 0.25f * acc[i][1] + bb0.y + x0.y;
            o[i][2] = 0.25f * acc[i][2] + bb0.z + x0.z;
            o[i][3] = 0.25f * acc[i][3] + bb0.w + x0.w;
            o[i][4] = 0.25f * acc[i][4] + bb1.x + x1.x;
            o[i][5] = 0.25f * acc[i][5] + bb1.y + x1.y;
            o[i][6] = 0.25f * acc[i][6] + bb1.z + x1.z;
            o[i][7] = 0.25f * acc[i][7] + bb1.w + x1.w;
            if (has_next) {
                *(float4*)(out + (size_t)n * 64 + c0) =
                    make_float4(o[i][0], o[i][1], o[i][2], o[i][3]);
                *(float4*)(out + (size_t)n * 64 + c0 + 4) =
                    make_float4(o[i][4], o[i][5], o[i][6], o[i][7]);
            }
        } else {
#pragma unroll
            for (int qq = 0; qq < 8; ++qq) o[i][qq] = 0.f;
        }
    }

    if (has_next) {
        float pj[2][8];
#pragma unroll
        for (int i = 0; i < 2; ++i)
#pragma unroll
            for (int jj = 0; jj < 8; ++jj) pj[i][jj] = 0.f;
#pragma unroll
        for (int cidx = 0; cidx < 8; ++cidx) {
#pragma unroll
            for (int jj = 0; jj < 8; ++jj) {
                const float vv = vN[(c0 + cidx) * 8 + jj];
                pj[0][jj] += o[0][cidx] * vv;
                pj[1][jj] += o[1][cidx] * vv;
            }
        }
#pragma unroll
        for (int off = 1; off < 8; off <<= 1) {
#pragma unroll
            for (int i = 0; i < 2; ++i)
#pragma unroll
                for (int jj = 0; jj < 8; ++jj)
                    pj[i][jj] += __shfl_xor(pj[i][jj], off);
        }
        if (cg == 0) {
#pragma unroll
            for (int i = 0; i < 2; ++i) {
                const int n = n0 + ng * 2 + i;
                if (n < n_nodes) {
#pragma unroll
                    for (int h = 0; h < 4; ++h) {
                        asrc[n * 4 + h] = pj[i][h];
                        adst[n * 4 + h] = pj[i][4 + h];
                    }
                }
            }
        }
        return;
    }

    // ---- fused output MLP (last layer): h3 tile -> 64 -> 32 -> 8 ----
    __syncthreads();  // all k-loop reads of gS done before overwrite
    // h3 into gS cols 0..63
#pragma unroll
    for (int i = 0; i < 2; ++i) {
        const int nl = ng * 2 + i;
        *(float4*)(gS + nl * GSTR + c0)     = make_float4(o[i][0], o[i][1], o[i][2], o[i][3]);
        *(float4*)(gS + nl * GSTR + c0 + 4) = make_float4(o[i][4], o[i][5], o[i][6], o[i][7]);
    }
    // stage W1 (64x64) and W2 (64x32) into Wp; b1,b2,b3,W3 into vN
    {
        const int f4 = t;  // W1: 1024 float4
#pragma unroll
        for (int j = 0; j < 4; ++j)
            *(float4*)(Wp + (j * 256 + t) * 4) = *(const float4*)(Wm1 + (j * 256 + t) * 4);
#pragma unroll
        for (int j = 0; j < 2; ++j)
            *(float4*)(Wp + 4096 + (j * 256 + t) * 4) = *(const float4*)(Wm2 + (j * 256 + t) * 4);
        if (t < 64) vN[t] = bm1[t];
        else if (t < 96) vN[t] = bm2[t - 64];
        else if (t < 104) vN[t] = bm3[t - 96];
        if (t < 256) vN[104 + t] = Wm3[t];
        (void)f4;
    }
    __syncthreads();
    // layer 1: o1[n][j] = elu(b1[j] + sum_k h3[n][k] * W1[k][j])
    // thread: cols j = c0..c0+7, nodes 2ng,2ng+1. Write o1S = gS cols 64..127.
    {
        float a1[2][8];
#pragma unroll
        for (int i = 0; i < 2; ++i)
#pragma unroll
            for (int qq = 0; qq < 8; ++qq) a1[i][qq] = vN[c0 + qq];
#pragma unroll 4
        for (int k = 0; k < 64; ++k) {
            const float h0 = gS[(ng * 2 + 0) * GSTR + k];
            const float h1v = gS[(ng * 2 + 1) * GSTR + k];
            const float4 w0 = *(const float4*)(Wp + k * 64 + c0);
            const float4 w1 = *(const float4*)(Wp + k * 64 + c0 + 4);
            a1[0][0] += h0 * w0.x; a1[0][1] += h0 * w0.y;
            a1[0][2] += h0 * w0.z; a1[0][3] += h0 * w0.w;
            a1[0][4] += h0 * w1.x; a1[0][5] += h0 * w1.y;
            a1[0][6] += h0 * w1.z; a1[0][7] += h0 * w1.w;
            a1[1][0] += h1v * w0.x; a1[1][1] += h1v * w0.y;
            a1[1][2] += h1v * w0.z; a1[1][3] += h1v * w0.w;
            a1[1][4] += h1v * w1.x; a1[1][5] += h1v * w1.y;
            a1[1][6] += h1v * w1.z; a1[1][7] += h1v * w1.w;
        }
#pragma unroll
        for (int i = 0; i < 2; ++i) {
            const int nl = ng * 2 + i;
            float4 v0 = make_float4(elu_f(a1[i][0]), elu_f(a1[i][1]), elu_f(a1[i][2]), elu_f(a1[i][3]));
            float4 v1 = make_float4(elu_f(a1[i][4]), elu_f(a1[i][5]), elu_f(a1[i][6]), elu_f(a1[i][7]));
            *(float4*)(gS + nl * GSTR + 64 + c0)     = v0;
            *(float4*)(gS + nl * GSTR + 64 + c0 + 4) = v1;
        }
    }
    __syncthreads();
    // layer 2: o2[n][c2] = elu(b2 + sum_j o1[n][j] * W2[j][c2]), c2 in 0..31
    // thread: cg4 = t&3 -> cols 8*cg4..+7; nn = t>>2 -> node 0..63.
    // Write o2S = gS cols 0..31 (h3 region, dead now).
    {
        const int cg4 = t & 3;
        const int nn = t >> 2;
        const int cc0 = cg4 * 8;
        float a2[8];
#pragma unroll
        for (int qq = 0; qq < 8; ++qq) a2[qq] = vN[64 + cc0 + qq];
#pragma unroll 4
        for (int j = 0; j < 64; ++j) {
            const float ov = gS[nn * GSTR + 64 + j];
            const float4 w0 = *(const float4*)(Wp + 4096 + j * 32 + cc0);
            const float4 w1 = *(const float4*)(Wp + 4096 + j * 32 + cc0 + 4);
            a2[0] += ov * w0.x; a2[1] += ov * w0.y;
            a2[2] += ov * w0.z; a2[3] += ov * w0.w;
            a2[4] += ov * w1.x; a2[5] += ov * w1.y;
            a2[6] += ov * w1.z; a2[7] += ov * w1.w;
        }
        __syncthreads();  // o1S reads done before overwriting gS cols 0..31
        *(float4*)(gS + nn * GSTR + cc0)     = make_float4(elu_f(a2[0]), elu_f(a2[1]), elu_f(a2[2]), elu_f(a2[3]));
        *(float4*)(gS + nn * GSTR + cc0 + 4) = make_float4(elu_f(a2[4]), elu_f(a2[5]), elu_f(a2[6]), elu_f(a2[7]));
    }
    __syncthreads();
    // layer 3: out[n][c3] = b3 + sum_j o2[n][j] * W3[j][c3], c3 in 0..7
    // thread: c3 = t&7, nq = t>>3 -> nodes 2nq, 2nq+1.
    {
        const int c3 = t & 7;
        const int nq = t >> 3;
#pragma unroll
        for (int i = 0; i < 2; ++i) {
            const int nl = nq * 2 + i;
            const int n = n0 + nl;
            if (n >= n_nodes) continue;
            float a3 = vN[96 + c3];
#pragma unroll 4
            for (int j = 0; j < 32; ++j)
                a3 += gS[nl * GSTR + j] * vN[104 + j * 8 + c3];
            mlp_out[(size_t)n * 8 + c3] = a3;
        }
    }
}

// ---------------------------------------------------------------------------
extern "C" void kernel_launch(void* const* d_in, const int* in_sizes, int n_in,
                              void* d_out, int out_size, void* d_ws, size_t ws_size,
                              hipStream_t stream) {
    const float* x     = (const float*)d_in[0];
    const int*   ei    = (const int*)d_in[1];
    const float* Wenc1 = (const float*)d_in[2];
    const float* benc1 = (const float*)d_in[3];
    const float* Wenc2 = (const float*)d_in[4];
    const float* benc2 = (const float*)d_in[5];
    const float* Wg[3]  = {(const float*)d_in[6],  (const float*)d_in[10], (const float*)d_in[14]};
    const float* as_[3] = {(const float*)d_in[7],  (const float*)d_in[11], (const float*)d_in[15]};
    const float* ad_[3] = {(const float*)d_in[8],  (const float*)d_in[12], (const float*)d_in[16]};
    const float* bg[3]  = {(const float*)d_in[9],  (const float*)d_in[13], (const float*)d_in[17]};
    const float* Wo1 = (const float*)d_in[18];
    const float* bo1 = (const float*)d_in[19];
    const float* Wo2 = (const float*)d_in[20];
    const float* bo2 = (const float*)d_in[21];
    const float* Wo3 = (const float*)d_in[22];
    const float* bo3 = (const float*)d_in[23];

    const int N = in_sizes[0] / 8;
    const int E = in_sizes[1] / 2;
    const int Etot = E + N;
    const int nblk = (N + SCAN_B - 1) / SCAN_B;  // 79

    float* buf0  = (float*)d_ws;                  // N*64
    float* buf1  = buf0 + (size_t)N * 64;         // N*64
    float* g     = buf1 + (size_t)N * 64;         // N*256
    float* asrc  = g + (size_t)N * 256;           // N*4
    float* adst  = asrc + (size_t)N * 4;          // N*4
    float* vfold = adst + (size_t)N * 4;          // 3*512
    int* rowptr = (int*)(vfold + 3 * 512);        // N+1 (+pad)
    int* cursor = rowptr + (N + 2);               // N
    int* cnt    = cursor + N;                     // N
    int* ready  = cnt + N;                        // 128
    int* flag   = ready + 128;                    // 1 (+pad)
    int* col    = flag + 2;                       // Etot

    // ---- P0: zero + detect + fold (one launch) ----
    prep_kernel<<<nblk + 6, 256, 0, stream>>>(ei,
        Wg[0], as_[0], ad_[0], Wg[1], as_[1], ad_[1], Wg[2], as_[2], ad_[2],
        cnt, ready, flag, vfold, N);
    count_kernel<<<(Etot + 255) / 256, 256, 0, stream>>>(ei, flag, E, Etot, cnt);
    scan_onepass_kernel<<<nblk, SCAN_B, 0, stream>>>(cnt, ready, rowptr, cursor, N);
    fill_kernel<<<(Etot + 255) / 256, 256, 0, stream>>>(ei, flag, E, Etot, cursor, col);

    // ---- encoder (+ layer-0 dots) ----
    encoder_kernel<<<(N + 255) / 256, 256, 0, stream>>>(x, Wenc1, benc1, Wenc2, benc2,
                                                        vfold, buf0, asrc, adst, N);

    // ---- 3 GAT layers; last post fuses the output MLP ----
    float* bin = buf0;
    float* bout = buf1;
    for (int l = 0; l < 3; ++l) {
        gat_agg_kernel<<<(N + 15) / 16, 256, 0, stream>>>(bin, asrc, adst, rowptr, col,
                                                          g, N);
        const int has_next = (l < 2) ? 1 : 0;
        gat_post_kernel<<<(N + 63) / 64, 256, 0, stream>>>(
            g, Wg[l], bg[l], bin, vfold + (l + 1 < 3 ? (l + 1) * 512 : 0), has_next,
            bout, asrc, adst,
            Wo1, bo1, Wo2, bo2, Wo3, bo3, (float*)d_out, N);
        float* tmp = bin; bin = bout; bout = tmp;
    }
}

// Round 8
// 287.528 us; speedup vs baseline: 1.5461x; 1.0614x over previous
//
#include <hip/hip_runtime.h>
#include <cstdint>
#include <cstddef>

#define NEG_SLOPE 0.2f

__device__ __forceinline__ float elu_f(float x) {
    return x > 0.f ? x : expm1f(x);
}

// ---------------------------------------------------------------------------
// P0: zero cnt + ready, detect edge-index layout, compute folded attention
// vectors for all 3 layers. Blocks 0..78 zero; blocks 79..84 fold.
// vfold[l][k*8+j] = sum_cc W_l[k, h*64+cc]*att[h,cc] (j<4 src, j>=4 dst, h=j&3)
// ---------------------------------------------------------------------------
__global__ __launch_bounds__(256) void prep_kernel(
    const int* __restrict__ ei,
    const float* __restrict__ W0, const float* __restrict__ as0, const float* __restrict__ ad0,
    const float* __restrict__ W1, const float* __restrict__ as1, const float* __restrict__ ad1,
    const float* __restrict__ W2, const float* __restrict__ as2, const float* __restrict__ ad2,
    int* __restrict__ cnt, int* __restrict__ ready, int* __restrict__ flag,
    float* __restrict__ vfold, int n) {
    const int b = blockIdx.x, t = threadIdx.x;
    if (b < 79) {
        const int i = b * 256 + t;
        if (i < n) cnt[i] = 0;
        if (b == 0) {
            if (t < 128) ready[t] = 0;
            if (t == 0) {
                int acc = 0;
#pragma unroll
                for (int k = 0; k < 8; ++k) acc |= ei[2 * k + 1];
                flag[0] = (acc == 0) ? 1 : 0;
            }
        }
        return;
    }
    const int e = (b - 79) * 256 + t;
    if (e >= 1536) return;
    const int l = e >> 9, rem = e & 511;
    const int k = rem >> 3, j = rem & 7, h = j & 3;
    const float* W   = (l == 0) ? W0  : (l == 1) ? W1  : W2;
    const float* as_ = (l == 0) ? as0 : (l == 1) ? as1 : as2;
    const float* ad_ = (l == 0) ? ad0 : (l == 1) ? ad1 : ad2;
    const float* av = (j < 4) ? as_ : ad_;
    const float* wr = W + k * 256 + h * 64;
    const float* ar = av + h * 64;
    float s = 0.f;
#pragma unroll 8
    for (int cc = 0; cc < 64; ++cc) s += wr[cc] * ar[cc];
    vfold[l * 512 + k * 8 + j] = s;
}

__global__ void count_kernel(const int* __restrict__ ei, const int* __restrict__ flag,
                             int E, int Etot, int* __restrict__ cnt) {
    int e = blockIdx.x * blockDim.x + threadIdx.x;
    if (e >= Etot) return;
    int d;
    if (e < E) d = flag[0] ? ei[2 * (size_t)(E + e)] : ei[E + e];
    else       d = e - E;  // self loop
    atomicAdd(&cnt[d], 1);
}

// ---------------------------------------------------------------------------
// One-pass scan with parallel lookback (79 co-resident blocks).
// ---------------------------------------------------------------------------
#define SCAN_B 256
__global__ __launch_bounds__(256) void scan_onepass_kernel(
    const int* __restrict__ cnt, int* __restrict__ ready,
    int* __restrict__ rowptr, int* __restrict__ cursor, int n) {
    __shared__ int sd[SCAN_B];
    __shared__ int sred[128];
    __shared__ int s_pref;
    const int b = blockIdx.x, t = threadIdx.x;
    const int g = b * SCAN_B + t;
    const int v = (g < n) ? cnt[g] : 0;
    sd[t] = v;
    __syncthreads();
    for (int off = 1; off < SCAN_B; off <<= 1) {
        int add = (t >= off) ? sd[t - off] : 0;
        __syncthreads();
        sd[t] += add;
        __syncthreads();
    }
    if (t == SCAN_B - 1) atomicExch(&ready[b], sd[SCAN_B - 1] + 1);
    if (t < 128) {
        int pv = 0;
        if (t < b) {
            do { pv = atomicAdd(&ready[t], 0); __builtin_amdgcn_s_sleep(1); } while (pv == 0);
            pv -= 1;
        }
        sred[t] = pv;
    }
    __syncthreads();
    if (t == 0) {
        int s = 0;
#pragma unroll 8
        for (int i = 0; i < 128; ++i) s += sred[i];
        s_pref = s;
    }
    __syncthreads();
    const int pre = s_pref;
    if (g < n) {
        const int e = pre + sd[t];
        rowptr[g + 1] = e;
        cursor[g] = e - v;
        if (g == 0) rowptr[0] = 0;
    }
}

__global__ void fill_kernel(const int* __restrict__ ei, const int* __restrict__ flag,
                            int E, int Etot, int* __restrict__ cursor,
                            int* __restrict__ col) {
    int e = blockIdx.x * blockDim.x + threadIdx.x;
    if (e >= Etot) return;
    int s, d;
    if (e < E) {
        if (flag[0]) { s = ei[2 * (size_t)e]; d = ei[2 * (size_t)(E + e)]; }
        else         { s = ei[e];             d = ei[E + e]; }
    } else {
        s = d = e - E;
    }
    int pos = atomicAdd(&cursor[d], 1);
    col[pos] = s;
}

// ---------------------------------------------------------------------------
// Encoder v2: LDS-tiled GEMM, 64 nodes/block (313 blocks), + layer-0 dots.
// Phase A: h1 = elu(x@W1+b1) into transposed LDS tile h1T[32][stride 68]
//   (stride 68: 16B-aligned rows, phase-B banks 4*nq -> conflict-free).
// Phase B: 4-node x 4-col micro-tile; per k: b128 h-read (broadcast) +
//   b128 W2-read + 16 FMA. Dots fused from registers (shfl over 16 cg lanes).
// ---------------------------------------------------------------------------
#define H1STR 68
__global__ __launch_bounds__(256) void encoder_kernel(
    const float* __restrict__ x,
    const float* __restrict__ W1, const float* __restrict__ b1,
    const float* __restrict__ W2, const float* __restrict__ b2,
    const float* __restrict__ vfold0,
    float* __restrict__ h0, float* __restrict__ asrc, float* __restrict__ adst,
    int n_nodes) {
    __shared__ float W1s[256];
    __shared__ float b1s[32];
    __shared__ float W2s[2048];
    __shared__ float b2s[64];
    __shared__ float vsd[512];
    __shared__ float xS[512];            // 64 nodes x 8
    __shared__ float h1T[32 * H1STR];    // [k][node]
    const int t = threadIdx.x;
    const int n0 = blockIdx.x * 64;
    const int rem = n_nodes - n0;        // nodes in this block (may be <64)

    // ---- stage ----
    *(float4*)(W2s + t * 4) = *(const float4*)(W2 + t * 4);
    *(float4*)(W2s + 1024 + t * 4) = *(const float4*)(W2 + 1024 + t * 4);
    if (t < 64)  *(float4*)(W1s + t * 4) = *(const float4*)(W1 + t * 4);
    if (t < 8)   *(float4*)(b1s + t * 4) = *(const float4*)(b1 + t * 4);
    if (t < 16)  *(float4*)(b2s + t * 4) = *(const float4*)(b2 + t * 4);
    if (t < 128) *(float4*)(vsd + t * 4) = *(const float4*)(vfold0 + t * 4);
    if (t < 128) {
        const int fidx = t * 4;  // float offset in tile (0..511)
        float4 v = make_float4(0.f, 0.f, 0.f, 0.f);
        if (fidx < rem * 8) v = *(const float4*)(x + (size_t)n0 * 8 + fidx);
        *(float4*)(xS + fidx) = v;
    }
    __syncthreads();

    // ---- phase A: h1 (64 nodes x 32), thread = (node, 8-col group) ----
    {
        const int nl = t >> 2;           // 0..63
        const int j0 = (t & 3) * 8;      // 0,8,16,24
        const float4 xa = *(const float4*)(xS + nl * 8);
        const float4 xb = *(const float4*)(xS + nl * 8 + 4);
        const float xk[8] = {xa.x, xa.y, xa.z, xa.w, xb.x, xb.y, xb.z, xb.w};
        float a[8];
#pragma unroll
        for (int u = 0; u < 8; ++u) a[u] = b1s[j0 + u];
#pragma unroll
        for (int k = 0; k < 8; ++k) {
            const float4 w0 = *(const float4*)(W1s + k * 32 + j0);
            const float4 w1 = *(const float4*)(W1s + k * 32 + j0 + 4);
            a[0] += xk[k] * w0.x; a[1] += xk[k] * w0.y;
            a[2] += xk[k] * w0.z; a[3] += xk[k] * w0.w;
            a[4] += xk[k] * w1.x; a[5] += xk[k] * w1.y;
            a[6] += xk[k] * w1.z; a[7] += xk[k] * w1.w;
        }
#pragma unroll
        for (int u = 0; u < 8; ++u) h1T[(j0 + u) * H1STR + nl] = elu_f(a[u]);
    }
    __syncthreads();

    // ---- phase B: out (64 nodes x 64), thread = (4 nodes, 4 cols) ----
    const int cg = t & 15;   // col group: cols cg*4..+3
    const int nq = t >> 4;   // node group: nodes nq*4..+3
    const int c0 = cg * 4;
    float acc[4][4];
#pragma unroll
    for (int i = 0; i < 4; ++i)
#pragma unroll
        for (int c = 0; c < 4; ++c) acc[i][c] = b2s[c0 + c];
#pragma unroll 8
    for (int k = 0; k < 32; ++k) {
        const float4 hv = *(const float4*)(h1T + k * H1STR + nq * 4);
        const float4 wv = *(const float4*)(W2s + k * 64 + c0);
        const float hvv[4] = {hv.x, hv.y, hv.z, hv.w};
#pragma unroll
        for (int i = 0; i < 4; ++i) {
            acc[i][0] += hvv[i] * wv.x; acc[i][1] += hvv[i] * wv.y;
            acc[i][2] += hvv[i] * wv.z; acc[i][3] += hvv[i] * wv.w;
        }
    }
    float o[4][4];
#pragma unroll
    for (int i = 0; i < 4; ++i)
#pragma unroll
        for (int c = 0; c < 4; ++c) o[i][c] = elu_f(acc[i][c]);

    // write h0
#pragma unroll
    for (int i = 0; i < 4; ++i) {
        const int n = n0 + nq * 4 + i;
        if (n < n_nodes)
            *(float4*)(h0 + (size_t)n * 64 + c0) =
                make_float4(o[i][0], o[i][1], o[i][2], o[i][3]);
    }
    // fused layer-0 dots
    float ad[4][8];
#pragma unroll
    for (int i = 0; i < 4; ++i)
#pragma unroll
        for (int jj = 0; jj < 8; ++jj) ad[i][jj] = 0.f;
#pragma unroll
    for (int c = 0; c < 4; ++c) {
        const float4 v0 = *(const float4*)(vsd + (c0 + c) * 8);
        const float4 v1 = *(const float4*)(vsd + (c0 + c) * 8 + 4);
#pragma unroll
        for (int i = 0; i < 4; ++i) {
            ad[i][0] += o[i][c] * v0.x; ad[i][1] += o[i][c] * v0.y;
            ad[i][2] += o[i][c] * v0.z; ad[i][3] += o[i][c] * v0.w;
            ad[i][4] += o[i][c] * v1.x; ad[i][5] += o[i][c] * v1.y;
            ad[i][6] += o[i][c] * v1.z; ad[i][7] += o[i][c] * v1.w;
        }
    }
#pragma unroll
    for (int off = 1; off < 16; off <<= 1) {
#pragma unroll
        for (int i = 0; i < 4; ++i)
#pragma unroll
            for (int jj = 0; jj < 8; ++jj)
                ad[i][jj] += __shfl_xor(ad[i][jj], off);
    }
    if (cg == 0) {
#pragma unroll
        for (int i = 0; i < 4; ++i) {
            const int n = n0 + nq * 4 + i;
            if (n < n_nodes) {
#pragma unroll
                for (int h = 0; h < 4; ++h) {
                    asrc[n * 4 + h] = ad[i][h];
                    adst[n * 4 + h] = ad[i][4 + h];
                }
            }
        }
    }
}

// ---------------------------------------------------------------------------
// GAT aggregation: one 16-lane group per dst node (4 nodes/wave, 16/block).
// ---------------------------------------------------------------------------
__global__ __launch_bounds__(256) void gat_agg_kernel(
    const float* __restrict__ bin, const float* __restrict__ asrc,
    const float* __restrict__ adst, const int* __restrict__ rowptr,
    const int* __restrict__ col, float* __restrict__ g, int n_nodes) {
    const int grp = threadIdx.x >> 4;
    const int q = threadIdx.x & 15;
    const int n = blockIdx.x * 16 + grp;
    if (n >= n_nodes) return;
    const float4 ad4 = *(const float4*)(adst + (size_t)n * 4);
    const int start = rowptr[n], end = rowptr[n + 1];

    float acc[4][4];
#pragma unroll
    for (int h = 0; h < 4; ++h)
#pragma unroll
        for (int z = 0; z < 4; ++z) acc[h][z] = 0.f;
    float4 den4 = make_float4(0.f, 0.f, 0.f, 0.f);

    for (int base = start; base < end; base += 16) {
        const int cnt = min(16, end - base);
        int c = 0;
        float4 w4 = make_float4(0.f, 0.f, 0.f, 0.f);
        if (base + q < end) {
            c = col[base + q];
            const float4 av = *(const float4*)(asrc + (size_t)c * 4);
            float l0 = av.x + ad4.x; l0 = l0 > 0.f ? l0 : NEG_SLOPE * l0;
            float l1 = av.y + ad4.y; l1 = l1 > 0.f ? l1 : NEG_SLOPE * l1;
            float l2 = av.z + ad4.z; l2 = l2 > 0.f ? l2 : NEG_SLOPE * l2;
            float l3 = av.w + ad4.w; l3 = l3 > 0.f ? l3 : NEG_SLOPE * l3;
            w4.x = __expf(fminf(l0, 60.f));
            w4.y = __expf(fminf(l1, 60.f));
            w4.z = __expf(fminf(l2, 60.f));
            w4.w = __expf(fminf(l3, 60.f));
            den4.x += w4.x; den4.y += w4.y; den4.z += w4.z; den4.w += w4.w;
        }
        int j = 0;
        for (; j + 4 <= cnt; j += 4) {
#pragma unroll
            for (int u = 0; u < 4; ++u) {
                const int s = __shfl(c, j + u, 16);
                const float4 hv = *(const float4*)(bin + (size_t)s * 64 + q * 4);
                const float wx = __shfl(w4.x, j + u, 16);
                const float wy = __shfl(w4.y, j + u, 16);
                const float wz = __shfl(w4.z, j + u, 16);
                const float ww = __shfl(w4.w, j + u, 16);
                acc[0][0] += wx * hv.x; acc[0][1] += wx * hv.y;
                acc[0][2] += wx * hv.z; acc[0][3] += wx * hv.w;
                acc[1][0] += wy * hv.x; acc[1][1] += wy * hv.y;
                acc[1][2] += wy * hv.z; acc[1][3] += wy * hv.w;
                acc[2][0] += wz * hv.x; acc[2][1] += wz * hv.y;
                acc[2][2] += wz * hv.z; acc[2][3] += wz * hv.w;
                acc[3][0] += ww * hv.x; acc[3][1] += ww * hv.y;
                acc[3][2] += ww * hv.z; acc[3][3] += ww * hv.w;
            }
        }
        for (; j < cnt; ++j) {
            const int s = __shfl(c, j, 16);
            const float4 hv = *(const float4*)(bin + (size_t)s * 64 + q * 4);
            const float wx = __shfl(w4.x, j, 16);
            const float wy = __shfl(w4.y, j, 16);
            const float wz = __shfl(w4.z, j, 16);
            const float ww = __shfl(w4.w, j, 16);
            acc[0][0] += wx * hv.x; acc[0][1] += wx * hv.y;
            acc[0][2] += wx * hv.z; acc[0][3] += wx * hv.w;
            acc[1][0] += wy * hv.x; acc[1][1] += wy * hv.y;
            acc[1][2] += wy * hv.z; acc[1][3] += wy * hv.w;
            acc[2][0] += wz * hv.x; acc[2][1] += wz * hv.y;
            acc[2][2] += wz * hv.z; acc[2][3] += wz * hv.w;
            acc[3][0] += ww * hv.x; acc[3][1] += ww * hv.y;
            acc[3][2] += ww * hv.z; acc[3][3] += ww * hv.w;
        }
    }
#pragma unroll
    for (int off = 1; off < 16; off <<= 1) {
        den4.x += __shfl_xor(den4.x, off, 16);
        den4.y += __shfl_xor(den4.y, off, 16);
        den4.z += __shfl_xor(den4.z, off, 16);
        den4.w += __shfl_xor(den4.w, off, 16);
    }
    const float i0 = 1.f / (den4.x + 1e-16f);
    const float i1 = 1.f / (den4.y + 1e-16f);
    const float i2 = 1.f / (den4.z + 1e-16f);
    const float i3 = 1.f / (den4.w + 1e-16f);
    float* gr = g + (size_t)n * 256 + q * 4;
    *(float4*)(gr +   0) = make_float4(acc[0][0]*i0, acc[0][1]*i0, acc[0][2]*i0, acc[0][3]*i0);
    *(float4*)(gr +  64) = make_float4(acc[1][0]*i1, acc[1][1]*i1, acc[1][2]*i1, acc[1][3]*i1);
    *(float4*)(gr + 128) = make_float4(acc[2][0]*i2, acc[2][1]*i2, acc[2][2]*i2, acc[2][3]*i2);
    *(float4*)(gr + 192) = make_float4(acc[3][0]*i3, acc[3][1]*i3, acc[3][2]*i3, acc[3][3]*i3);
}

// ---------------------------------------------------------------------------
// GAT post-projection. has_next=1: fused next-layer dots. has_next=0: fused
// output MLP 64->64->32->8 (h3 never hits global; writes d_out).
// ---------------------------------------------------------------------------
#define GSTR 132
__global__ __launch_bounds__(256) void gat_post_kernel(
    const float* __restrict__ g, const float* __restrict__ W,
    const float* __restrict__ bias, const float* __restrict__ xin,
    const float* __restrict__ vfold_next, int has_next,
    float* __restrict__ out, float* __restrict__ asrc, float* __restrict__ adst,
    const float* __restrict__ Wm1, const float* __restrict__ bm1,
    const float* __restrict__ Wm2, const float* __restrict__ bm2,
    const float* __restrict__ Wm3, const float* __restrict__ bm3,
    float* __restrict__ mlp_out, int n_nodes) {
    __shared__ float gS[64 * GSTR];  // 33,792 B
    __shared__ float Wp[128 * 64];   // 32,768 B
    __shared__ float vN[512];        //  2,048 B
    const int t = threadIdx.x;
    const int n0 = blockIdx.x * 64;
    const int cg = t & 7;
    const int ng = t >> 3;

    if (has_next && t < 128) *(float4*)(vN + t * 4) = *(const float4*)(vfold_next + t * 4);

    float acc[2][8];
#pragma unroll
    for (int i = 0; i < 2; ++i)
#pragma unroll
        for (int qq = 0; qq < 8; ++qq) acc[i][qq] = 0.f;

    for (int slab = 0; slab < 2; ++slab) {
        __syncthreads();
#pragma unroll
        for (int j = 0; j < 8; ++j) {
            const int idx = j * 256 + t;
            const int nl = idx >> 5;
            const int c4 = idx & 31;
            float4 v = make_float4(0.f, 0.f, 0.f, 0.f);
            if (n0 + nl < n_nodes)
                v = *(const float4*)(g + (size_t)(n0 + nl) * 256 + slab * 128 + c4 * 4);
            *(float4*)(gS + nl * GSTR + c4 * 4) = v;
        }
#pragma unroll
        for (int j = 0; j < 8; ++j) {
            const int f4 = j * 256 + t;
            const int kl = f4 >> 4;
            const int kap = slab * 128 + kl;
            const int h = kap >> 6, kk = kap & 63;
            const int c = (f4 & 15) * 4;
            *(float4*)(Wp + kl * 64 + c) = *(const float4*)(W + kk * 256 + h * 64 + c);
        }
        __syncthreads();
#pragma unroll 4
        for (int kl = 0; kl < 128; ++kl) {
            const float a0 = gS[(ng * 2 + 0) * GSTR + kl];
            const float a1 = gS[(ng * 2 + 1) * GSTR + kl];
            const float4 b0 = *(const float4*)(Wp + kl * 64 + cg * 8);
            const float4 b1 = *(const float4*)(Wp + kl * 64 + cg * 8 + 4);
            acc[0][0] += a0 * b0.x; acc[0][1] += a0 * b0.y;
            acc[0][2] += a0 * b0.z; acc[0][3] += a0 * b0.w;
            acc[0][4] += a0 * b1.x; acc[0][5] += a0 * b1.y;
            acc[0][6] += a0 * b1.z; acc[0][7] += a0 * b1.w;
            acc[1][0] += a1 * b0.x; acc[1][1] += a1 * b0.y;
            acc[1][2] += a1 * b0.z; acc[1][3] += a1 * b0.w;
            acc[1][4] += a1 * b1.x; acc[1][5] += a1 * b1.y;
            acc[1][6] += a1 * b1.z; acc[1][7] += a1 * b1.w;
        }
    }

    const int c0 = cg * 8;
    const float4 bb0 = *(const float4*)(bias + c0);
    const float4 bb1 = *(const float4*)(bias + c0 + 4);
    float o[2][8];
#pragma unroll
    for (int i = 0; i < 2; ++i) {
        const int n = n0 + ng * 2 + i;
        if (n < n_nodes) {
            const float4 x0 = *(const float4*)(xin + (size_t)n * 64 + c0);
            const float4 x1 = *(const float4*)(xin + (size_t)n * 64 + c0 + 4);
            o[i][0] = 0.25f * acc[i][0] + bb0.x + x0.x;
            o[i][1] = 0.25f * acc[i][1] + bb0.y + x0.y;
            o[i][2] = 0.25f * acc[i][2] + bb0.z + x0.z;
            o[i][3] = 0.25f * acc[i][3] + bb0.w + x0.w;
            o[i][4] = 0.25f * acc[i][4] + bb1.x + x1.x;
            o[i][5] = 0.25f * acc[i][5] + bb1.y + x1.y;
            o[i][6] = 0.25f * acc[i][6] + bb1.z + x1.z;
            o[i][7] = 0.25f * acc[i][7] + bb1.w + x1.w;
            if (has_next) {
                *(float4*)(out + (size_t)n * 64 + c0) =
                    make_float4(o[i][0], o[i][1], o[i][2], o[i][3]);
                *(float4*)(out + (size_t)n * 64 + c0 + 4) =
                    make_float4(o[i][4], o[i][5], o[i][6], o[i][7]);
            }
        } else {
#pragma unroll
            for (int qq = 0; qq < 8; ++qq) o[i][qq] = 0.f;
        }
    }

    if (has_next) {
        float pj[2][8];
#pragma unroll
        for (int i = 0; i < 2; ++i)
#pragma unroll
            for (int jj = 0; jj < 8; ++jj) pj[i][jj] = 0.f;
#pragma unroll
        for (int cidx = 0; cidx < 8; ++cidx) {
#pragma unroll
            for (int jj = 0; jj < 8; ++jj) {
                const float vv = vN[(c0 + cidx) * 8 + jj];
                pj[0][jj] += o[0][cidx] * vv;
                pj[1][jj] += o[1][cidx] * vv;
            }
        }
#pragma unroll
        for (int off = 1; off < 8; off <<= 1) {
#pragma unroll
            for (int i = 0; i < 2; ++i)
#pragma unroll
                for (int jj = 0; jj < 8; ++jj)
                    pj[i][jj] += __shfl_xor(pj[i][jj], off);
        }
        if (cg == 0) {
#pragma unroll
            for (int i = 0; i < 2; ++i) {
                const int n = n0 + ng * 2 + i;
                if (n < n_nodes) {
#pragma unroll
                    for (int h = 0; h < 4; ++h) {
                        asrc[n * 4 + h] = pj[i][h];
                        adst[n * 4 + h] = pj[i][4 + h];
                    }
                }
            }
        }
        return;
    }

    // ---- fused output MLP (last layer) ----
    __syncthreads();
#pragma unroll
    for (int i = 0; i < 2; ++i) {
        const int nl = ng * 2 + i;
        *(float4*)(gS + nl * GSTR + c0)     = make_float4(o[i][0], o[i][1], o[i][2], o[i][3]);
        *(float4*)(gS + nl * GSTR + c0 + 4) = make_float4(o[i][4], o[i][5], o[i][6], o[i][7]);
    }
    {
#pragma unroll
        for (int j = 0; j < 4; ++j)
            *(float4*)(Wp + (j * 256 + t) * 4) = *(const float4*)(Wm1 + (j * 256 + t) * 4);
#pragma unroll
        for (int j = 0; j < 2; ++j)
            *(float4*)(Wp + 4096 + (j * 256 + t) * 4) = *(const float4*)(Wm2 + (j * 256 + t) * 4);
        if (t < 64) vN[t] = bm1[t];
        else if (t < 96) vN[t] = bm2[t - 64];
        else if (t < 104) vN[t] = bm3[t - 96];
        vN[104 + t] = Wm3[t];
    }
    __syncthreads();
    {
        float a1[2][8];
#pragma unroll
        for (int i = 0; i < 2; ++i)
#pragma unroll
            for (int qq = 0; qq < 8; ++qq) a1[i][qq] = vN[c0 + qq];
#pragma unroll 4
        for (int k = 0; k < 64; ++k) {
            const float h0 = gS[(ng * 2 + 0) * GSTR + k];
            const float h1v = gS[(ng * 2 + 1) * GSTR + k];
            const float4 w0 = *(const float4*)(Wp + k * 64 + c0);
            const float4 w1 = *(const float4*)(Wp + k * 64 + c0 + 4);
            a1[0][0] += h0 * w0.x; a1[0][1] += h0 * w0.y;
            a1[0][2] += h0 * w0.z; a1[0][3] += h0 * w0.w;
            a1[0][4] += h0 * w1.x; a1[0][5] += h0 * w1.y;
            a1[0][6] += h0 * w1.z; a1[0][7] += h0 * w1.w;
            a1[1][0] += h1v * w0.x; a1[1][1] += h1v * w0.y;
            a1[1][2] += h1v * w0.z; a1[1][3] += h1v * w0.w;
            a1[1][4] += h1v * w1.x; a1[1][5] += h1v * w1.y;
            a1[1][6] += h1v * w1.z; a1[1][7] += h1v * w1.w;
        }
#pragma unroll
        for (int i = 0; i < 2; ++i) {
            const int nl = ng * 2 + i;
            float4 v0 = make_float4(elu_f(a1[i][0]), elu_f(a1[i][1]), elu_f(a1[i][2]), elu_f(a1[i][3]));
            float4 v1 = make_float4(elu_f(a1[i][4]), elu_f(a1[i][5]), elu_f(a1[i][6]), elu_f(a1[i][7]));
            *(float4*)(gS + nl * GSTR + 64 + c0)     = v0;
            *(float4*)(gS + nl * GSTR + 64 + c0 + 4) = v1;
        }
    }
    __syncthreads();
    {
        const int cg4 = t & 3;
        const int nn = t >> 2;
        const int cc0 = cg4 * 8;
        float a2[8];
#pragma unroll
        for (int qq = 0; qq < 8; ++qq) a2[qq] = vN[64 + cc0 + qq];
#pragma unroll 4
        for (int j = 0; j < 64; ++j) {
            const float ov = gS[nn * GSTR + 64 + j];
            const float4 w0 = *(const float4*)(Wp + 4096 + j * 32 + cc0);
            const float4 w1 = *(const float4*)(Wp + 4096 + j * 32 + cc0 + 4);
            a2[0] += ov * w0.x; a2[1] += ov * w0.y;
            a2[2] += ov * w0.z; a2[3] += ov * w0.w;
            a2[4] += ov * w1.x; a2[5] += ov * w1.y;
            a2[6] += ov * w1.z; a2[7] += ov * w1.w;
        }
        __syncthreads();
        *(float4*)(gS + nn * GSTR + cc0)     = make_float4(elu_f(a2[0]), elu_f(a2[1]), elu_f(a2[2]), elu_f(a2[3]));
        *(float4*)(gS + nn * GSTR + cc0 + 4) = make_float4(elu_f(a2[4]), elu_f(a2[5]), elu_f(a2[6]), elu_f(a2[7]));
    }
    __syncthreads();
    {
        const int c3 = t & 7;
        const int nq = t >> 3;
#pragma unroll
        for (int i = 0; i < 2; ++i) {
            const int nl = nq * 2 + i;
            const int n = n0 + nl;
            if (n >= n_nodes) continue;
            float a3 = vN[96 + c3];
#pragma unroll 4
            for (int j = 0; j < 32; ++j)
                a3 += gS[nl * GSTR + j] * vN[104 + j * 8 + c3];
            mlp_out[(size_t)n * 8 + c3] = a3;
        }
    }
}

// ---------------------------------------------------------------------------
extern "C" void kernel_launch(void* const* d_in, const int* in_sizes, int n_in,
                              void* d_out, int out_size, void* d_ws, size_t ws_size,
                              hipStream_t stream) {
    const float* x     = (const float*)d_in[0];
    const int*   ei    = (const int*)d_in[1];
    const float* Wenc1 = (const float*)d_in[2];
    const float* benc1 = (const float*)d_in[3];
    const float* Wenc2 = (const float*)d_in[4];
    const float* benc2 = (const float*)d_in[5];
    const float* Wg[3]  = {(const float*)d_in[6],  (const float*)d_in[10], (const float*)d_in[14]};
    const float* as_[3] = {(const float*)d_in[7],  (const float*)d_in[11], (const float*)d_in[15]};
    const float* ad_[3] = {(const float*)d_in[8],  (const float*)d_in[12], (const float*)d_in[16]};
    const float* bg[3]  = {(const float*)d_in[9],  (const float*)d_in[13], (const float*)d_in[17]};
    const float* Wo1 = (const float*)d_in[18];
    const float* bo1 = (const float*)d_in[19];
    const float* Wo2 = (const float*)d_in[20];
    const float* bo2 = (const float*)d_in[21];
    const float* Wo3 = (const float*)d_in[22];
    const float* bo3 = (const float*)d_in[23];

    const int N = in_sizes[0] / 8;
    const int E = in_sizes[1] / 2;
    const int Etot = E + N;
    const int nblk = (N + SCAN_B - 1) / SCAN_B;  // 79

    float* buf0  = (float*)d_ws;                  // N*64
    float* buf1  = buf0 + (size_t)N * 64;         // N*64
    float* g     = buf1 + (size_t)N * 64;         // N*256
    float* asrc  = g + (size_t)N * 256;           // N*4
    float* adst  = asrc + (size_t)N * 4;          // N*4
    float* vfold = adst + (size_t)N * 4;          // 3*512
    int* rowptr = (int*)(vfold + 3 * 512);        // N+1 (+pad)
    int* cursor = rowptr + (N + 2);               // N
    int* cnt    = cursor + N;                     // N
    int* ready  = cnt + N;                        // 128
    int* flag   = ready + 128;                    // 1 (+pad)
    int* col    = flag + 2;                       // Etot

    prep_kernel<<<nblk + 6, 256, 0, stream>>>(ei,
        Wg[0], as_[0], ad_[0], Wg[1], as_[1], ad_[1], Wg[2], as_[2], ad_[2],
        cnt, ready, flag, vfold, N);
    count_kernel<<<(Etot + 255) / 256, 256, 0, stream>>>(ei, flag, E, Etot, cnt);
    scan_onepass_kernel<<<nblk, SCAN_B, 0, stream>>>(cnt, ready, rowptr, cursor, N);
    fill_kernel<<<(Etot + 255) / 256, 256, 0, stream>>>(ei, flag, E, Etot, cursor, col);

    encoder_kernel<<<(N + 63) / 64, 256, 0, stream>>>(x, Wenc1, benc1, Wenc2, benc2,
                                                      vfold, buf0, asrc, adst, N);

    float* bin = buf0;
    float* bout = buf1;
    for (int l = 0; l < 3; ++l) {
        gat_agg_kernel<<<(N + 15) / 16, 256, 0, stream>>>(bin, asrc, adst, rowptr, col,
                                                          g, N);
        const int has_next = (l < 2) ? 1 : 0;
        gat_post_kernel<<<(N + 63) / 64, 256, 0, stream>>>(
            g, Wg[l], bg[l], bin, vfold + (l + 1 < 3 ? (l + 1) * 512 : 0), has_next,
            bout, asrc, adst,
            Wo1, bo1, Wo2, bo2, Wo3, bo3, (float*)d_out, N);
        float* tmp = bin; bin = bout; bout = tmp;
    }
}